// Round 13
// baseline (351.676 us; speedup 1.0000x reference)
//
#include <hip/hip_runtime.h>

typedef unsigned short u16;
typedef unsigned int   u32;
typedef __attribute__((ext_vector_type(8))) short short8v;
typedef __attribute__((ext_vector_type(8))) unsigned short us8;
typedef __attribute__((ext_vector_type(4))) float f32x4;

static __device__ __forceinline__ float bf2f(u16 u){ union{u32 i; float f;} v; v.i=(u32)u<<16; return v.f; }
static __device__ __forceinline__ u16 f2bf(float f){ union{float f; u32 i;} u; u.f=f; u32 r=u.i+0x7FFFu+((u.i>>16)&1u); return (u16)(r>>16); }
// HW packed f32->bf16 (RNE), 1 inst per pair [guide m240: no builtin on gfx950]
static __device__ __forceinline__ u32 cvtpk(float lo, float hi){
  u32 r; asm("v_cvt_pk_bf16_f32 %0, %1, %2" : "=v"(r) : "v"(lo), "v"(hi)); return r;
}

static __device__ __forceinline__ float ld1(const void* p, size_t i, int f32){
  return f32 ? ((const float*)p)[i] : bf2f(((const u16*)p)[i]);
}
static __device__ __forceinline__ float4 ld4(const void* p, size_t i, int f32){
  if (f32) return *((const float4*)((const float*)p + i));
  ushort4 v = *((const ushort4*)((const u16*)p + i));
  return make_float4(bf2f(v.x), bf2f(v.y), bf2f(v.z), bf2f(v.w));
}
static __device__ __forceinline__ void st4(void* p, size_t i, float4 v, int f32){
  if (f32) *((float4*)((float*)p + i)) = v;
  else { ushort4 o; o.x=f2bf(v.x); o.y=f2bf(v.y); o.z=f2bf(v.z); o.w=f2bf(v.w); *((ushort4*)((u16*)p + i)) = o; }
}
static __device__ __forceinline__ void st1(void* p, size_t i, float v, int f32){
  if (f32) ((float*)p)[i] = v; else ((u16*)p)[i] = f2bf(v);
}
static __device__ __forceinline__ int lde(const int* ei, size_t i, int i64){
  return i64 ? ei[2*i] : ei[i];
}
static __device__ __forceinline__ int clampi(int v, int lo, int hi){ return v<lo?lo:(v>hi?hi:v); }

// ---------------- runtime dtype detection ----------------
__global__ void detect_kernel(const u32* __restrict__ x, const int* __restrict__ ei,
                              int* __restrict__ flags){
  __shared__ int cnt[2];
  int t = threadIdx.x;
  if (t < 2) cnt[t] = 0;
  __syncthreads();
  int good = 0;
  for (int i = t; i < 4096; i += 256){
    u32 e = (x[i] >> 7) & 0xFFu;
    if (e >= 90u && e <= 150u) good++;
  }
  atomicAdd(&cnt[0], good);
  int nzodd = 0;
  for (int i = t; i < 2048; i += 256){
    if (ei[2*i+1] != 0) nzodd++;
  }
  atomicAdd(&cnt[1], nzodd);
  __syncthreads();
  if (t == 0){
    flags[0] = (cnt[0] < 2867) ? 1 : 0;
    flags[1] = (cnt[1] == 0) ? 1 : 0;
  }
}

// ---------------- CSR build (separate small kernels; csr stores src*512) ----------------
__global__ void count_kernel(const int* __restrict__ ei, int E, int N,
                             int* __restrict__ deg, const int* __restrict__ flags){
  int i64 = flags[1];
  int i = blockIdx.x*blockDim.x + threadIdx.x;
  int Et = E + N;
  if (i < Et){
    int d = (i < E) ? clampi(lde(ei, (size_t)E + i, i64), 0, N-1) : (i - E);
    atomicAdd(&deg[d], 1);
  }
}

__global__ __launch_bounds__(256) void scan1_kernel(const int* __restrict__ deg,
    int* __restrict__ offs, int* __restrict__ bsum, int N){
  __shared__ int sm[256];
  int t = threadIdx.x;
  int i = blockIdx.x*256 + t;
  int v = (i < N) ? deg[i] : 0;
  sm[t] = v; __syncthreads();
  #pragma unroll
  for (int off = 1; off < 256; off <<= 1){
    int u = (t >= off) ? sm[t-off] : 0;
    __syncthreads();
    sm[t] += u;
    __syncthreads();
  }
  if (i < N) offs[i] = sm[t] - v;
  if (t == 255) bsum[blockIdx.x] = sm[255];
}

__global__ __launch_bounds__(1024) void scan2_kernel(const int* __restrict__ bsum,
    int* __restrict__ bpre, int NB){
  __shared__ int sm[1024];
  int t = threadIdx.x;
  int v = (t < NB) ? bsum[t] : 0;
  sm[t] = v; __syncthreads();
  #pragma unroll
  for (int off = 1; off < 1024; off <<= 1){
    int u = (t >= off) ? sm[t-off] : 0;
    __syncthreads();
    sm[t] += u;
    __syncthreads();
  }
  if (t < NB) bpre[t] = sm[t] - v;
  if (t == 1023) bpre[NB] = sm[1023];
}

__global__ __launch_bounds__(256) void scan3_kernel(int* __restrict__ offs,
    int* __restrict__ cursor, const int* __restrict__ bpre, int N, int NB){
  int i = blockIdx.x*256 + threadIdx.x;
  if (i < N){
    int v = offs[i] + bpre[blockIdx.x];
    offs[i] = v; cursor[i] = v;
  }
  if (i == 0) offs[N] = bpre[NB];
}

__global__ void scatter_kernel(const int* __restrict__ ei, int E, int N,
    int* __restrict__ cursor, int* __restrict__ csr_boff, const int* __restrict__ flags){
  int i64 = flags[1];
  int i = blockIdx.x*blockDim.x + threadIdx.x;
  int Et = E + N;
  if (i < Et){
    int s, d;
    if (i < E){
      s = clampi(lde(ei, i, i64), 0, N-1);
      d = clampi(lde(ei, (size_t)E + i, i64), 0, N-1);
    } else { s = i - E; d = s; }
    int p = atomicAdd(&cursor[d], 1);
    csr_boff[p] = s * 512;
  }
}

// ---------------- prep: B transposes (32 blocks) + qpart (block 32) ----------------
__global__ __launch_bounds__(256) void prep_kernel(const void* __restrict__ B1,
    const void* __restrict__ B2, u16* __restrict__ BT1, u16* __restrict__ BT2,
    const void* __restrict__ query, const void* __restrict__ Wc, const void* __restrict__ bc,
    float* __restrict__ qp, int Q, const int* __restrict__ flags){
  int f32 = flags[0];
  int bid = blockIdx.x;
  if (bid < 32){
    const void* B = (bid >= 16) ? B2 : B1;
    u16* BT = (bid >= 16) ? BT2 : BT1;
    int rem = bid & 15;
    int k0 = (rem >> 2)*64, c0 = (rem & 3)*64;
    __shared__ u16 tile[64][65];
    int r0 = threadIdx.x >> 6, c = threadIdx.x & 63;
    for (int r = r0; r < 64; r += 4)
      tile[r][c] = f32 ? f2bf(((const float*)B)[(size_t)(k0+r)*256 + c0 + c])
                       : ((const u16*)B)[(size_t)(k0+r)*256 + c0 + c];
    __syncthreads();
    for (int j = r0; j < 64; j += 4)
      BT[(size_t)(c0+j)*256 + k0 + c] = tile[c][j];
  } else {
    int q = threadIdx.x >> 5, ln = threadIdx.x & 31;
    if (q >= Q) return;
    float s = 0.f;
    for (int j = ln; j < 256; j += 32) s += ld1(query, q*256 + j, f32) * ld1(Wc, j, f32);
    #pragma unroll
    for (int off = 16; off; off >>= 1) s += __shfl_down(s, off, 32);
    if (ln == 0) qp[q] = s + ld1(bc, 0, f32);
  }
}

// ---------------- LDS-free, barrier-free MFMA GEMM ----------------
// Block = 4 waves; wave = 64 rows x 64 cols (wave wn == head wn).
// B fragments read per-wave directly from L2-resident BT[col][k]; A direct from global.
// No LDS, no __syncthreads: compiler pipelines loads against MFMA across full k-unroll.
__global__ __launch_bounds__(256, 4) void gemm_mfma(const void* __restrict__ A,
    const u16* __restrict__ BT, u16* __restrict__ C, int M, int aIsInput,
    const int* __restrict__ flags, float* __restrict__ es, float* __restrict__ ed,
    const void* __restrict__ a_src, const void* __restrict__ a_dst){
  int af32 = aIsInput ? flags[0] : 0;
  int f32 = flags[0];
  int tid = threadIdx.x;
  int wn = tid >> 6, lane = tid & 63;
  int l15 = lane & 15, l4 = lane >> 4;
  int row0 = blockIdx.x * 64;
  const u16*  A16 = (const u16*)A;
  const float* A32 = (const float*)A;
  int arow[4];
  #pragma unroll
  for (int mi = 0; mi < 4; mi++)
    arow[mi] = min(row0 + mi*16 + l15, M-1);
  const u16* Bb = BT + (size_t)(wn*64 + l15)*256 + 8*l4;
  f32x4 acc[4][4] = {};
  #pragma unroll
  for (int k0 = 0; k0 < 256; k0 += 32){
    short8v a[4], b[4];
    if (af32){
      #pragma unroll
      for (int mi = 0; mi < 4; mi++){
        const float* ap = A32 + (size_t)arow[mi]*256 + k0 + 8*l4;
        float4 v0 = *(const float4*)ap, v1 = *(const float4*)(ap+4);
        union{ u32 w[4]; us8 v; } pk;
        pk.w[0] = cvtpk(v0.x, v0.y); pk.w[1] = cvtpk(v0.z, v0.w);
        pk.w[2] = cvtpk(v1.x, v1.y); pk.w[3] = cvtpk(v1.z, v1.w);
        a[mi] = *(short8v*)&pk.v;
      }
    } else {
      #pragma unroll
      for (int mi = 0; mi < 4; mi++)
        a[mi] = *(const short8v*)(A16 + (size_t)arow[mi]*256 + k0 + 8*l4);
    }
    #pragma unroll
    for (int ni = 0; ni < 4; ni++)
      b[ni] = *(const short8v*)(Bb + (size_t)ni*16*256 + k0);
    #pragma unroll
    for (int mi = 0; mi < 4; mi++)
      #pragma unroll
      for (int ni = 0; ni < 4; ni++)
        acc[mi][ni] = __builtin_amdgcn_mfma_f32_16x16x32_bf16(a[mi], b[ni], acc[mi][ni], 0, 0, 0);
  }
  // C store (verified mapping: col=l15, row=l4*4+r within 16x16)
  #pragma unroll
  for (int mi = 0; mi < 4; mi++){
    #pragma unroll
    for (int ni = 0; ni < 4; ni++){
      #pragma unroll
      for (int r = 0; r < 4; r++){
        int row = row0 + mi*16 + l4*4 + r;
        int col = wn*64 + ni*16 + l15;
        if (row < M) C[(size_t)row*256 + col] = f2bf(acc[mi][ni][r]);
      }
    }
  }
  // fused es/ed: wave wn == head wn; reduce over this wave's 64 cols
  float as_[4], ad_[4];
  #pragma unroll
  for (int ni = 0; ni < 4; ni++){
    as_[ni] = ld1(a_src, wn*64 + ni*16 + l15, f32);
    ad_[ni] = ld1(a_dst, wn*64 + ni*16 + l15, f32);
  }
  #pragma unroll
  for (int mi = 0; mi < 4; mi++){
    #pragma unroll
    for (int r = 0; r < 4; r++){
      float pe = acc[mi][0][r]*as_[0] + acc[mi][1][r]*as_[1]
               + acc[mi][2][r]*as_[2] + acc[mi][3][r]*as_[3];
      float pd = acc[mi][0][r]*ad_[0] + acc[mi][1][r]*ad_[1]
               + acc[mi][2][r]*ad_[2] + acc[mi][3][r]*ad_[3];
      #pragma unroll
      for (int off = 1; off < 16; off <<= 1){
        pe += __shfl_xor(pe, off, 64);
        pd += __shfl_xor(pd, off, 64);
      }
      if (l15 == 0){
        int row = row0 + mi*16 + l4*4 + r;
        if (row < M){
          es[(size_t)row*4 + wn] = pe;
          ed[(size_t)row*4 + wn] = pd;
        }
      }
    }
  }
}

// ---------------- fused aggregation (byte-offset CSR) + nscore epilogue ----------------
__global__ __launch_bounds__(256) void agg_kernel(const u16* __restrict__ h,
    const int* __restrict__ csr_boff, const int* __restrict__ offs,
    const float* __restrict__ es, const float* __restrict__ ed, int N,
    const void* __restrict__ bias, void* __restrict__ out, int do_relu, int outIsOutput,
    const int* __restrict__ flags, const void* __restrict__ Wc,
    const float* __restrict__ qp, int Q){
  int f32in = flags[0];
  int of32  = outIsOutput ? flags[0] : 0;
  int ln = threadIdx.x & 63;
  int n = blockIdx.x*4 + (threadIdx.x >> 6);
  if (n >= N) return;
  int beg = offs[n], end = offs[n+1];
  int hd = ln >> 4, c0 = ln*4;
  int hd4 = hd*4;
  size_t coff = (size_t)c0*2;
  const char* hbase = (const char*)h;
  const char* ebase = (const char*)es;
  float edn = ed[(size_t)n*4 + hd];
  float a0=0.f, a1=0.f, a2=0.f, a3=0.f, ws=0.f;
  int i = beg;
  for (; i + 8 <= end; i += 8){
    int bo[8]; float x[8]; ushort4 hv[8];
    #pragma unroll
    for (int j = 0; j < 8; j++) bo[j] = csr_boff[i+j];
    #pragma unroll
    for (int j = 0; j < 8; j++) x[j] = *(const float*)(ebase + (bo[j] >> 5) + hd4);
    #pragma unroll
    for (int j = 0; j < 8; j++) hv[j] = *(const ushort4*)(hbase + bo[j] + coff);
    #pragma unroll
    for (int j = 0; j < 8; j++){
      float t = x[j] + edn; t = (t > 0.f) ? t : 0.2f*t; t = fminf(t, 60.f);
      float w = __expf(t);
      a0 += w*bf2f(hv[j].x); a1 += w*bf2f(hv[j].y);
      a2 += w*bf2f(hv[j].z); a3 += w*bf2f(hv[j].w);
      ws += w;
    }
  }
  for (; i + 4 <= end; i += 4){
    int bo[4]; float x[4]; ushort4 hv[4];
    #pragma unroll
    for (int j = 0; j < 4; j++) bo[j] = csr_boff[i+j];
    #pragma unroll
    for (int j = 0; j < 4; j++) x[j] = *(const float*)(ebase + (bo[j] >> 5) + hd4);
    #pragma unroll
    for (int j = 0; j < 4; j++) hv[j] = *(const ushort4*)(hbase + bo[j] + coff);
    #pragma unroll
    for (int j = 0; j < 4; j++){
      float t = x[j] + edn; t = (t > 0.f) ? t : 0.2f*t; t = fminf(t, 60.f);
      float w = __expf(t);
      a0 += w*bf2f(hv[j].x); a1 += w*bf2f(hv[j].y);
      a2 += w*bf2f(hv[j].z); a3 += w*bf2f(hv[j].w);
      ws += w;
    }
  }
  for (; i < end; i++){
    int bo = csr_boff[i];
    float t = *(const float*)(ebase + (bo >> 5) + hd4) + edn;
    t = (t > 0.f) ? t : 0.2f*t; t = fminf(t, 60.f);
    float w = __expf(t);
    ushort4 hv = *(const ushort4*)(hbase + bo + coff);
    a0 += w*bf2f(hv.x); a1 += w*bf2f(hv.y);
    a2 += w*bf2f(hv.z); a3 += w*bf2f(hv.w);
    ws += w;
  }
  float inv = 1.f / (ws + 1e-16f);
  float4 bv = ld4(bias, c0, f32in);
  float4 ov = make_float4(a0*inv + bv.x, a1*inv + bv.y, a2*inv + bv.z, a3*inv + bv.w);
  if (do_relu){
    ov.x = fmaxf(ov.x, 0.f); ov.y = fmaxf(ov.y, 0.f);
    ov.z = fmaxf(ov.z, 0.f); ov.w = fmaxf(ov.w, 0.f);
  }
  st4(out, (size_t)n*256 + c0, ov, of32);
  if (outIsOutput){
    float4 wc4 = ld4(Wc, 256 + c0, f32in);
    float v = ov.x*wc4.x + ov.y*wc4.y + ov.z*wc4.z + ov.w*wc4.w;
    #pragma unroll
    for (int off = 1; off < 64; off <<= 1) v += __shfl_xor(v, off, 64);
    if (ln < Q) st1(out, (size_t)N*256 + (size_t)ln*N + n, qp[ln] + v, of32);
  }
}

extern "C" void kernel_launch(void* const* d_in, const int* in_sizes, int n_in,
                              void* d_out, int out_size, void* d_ws, size_t ws_size,
                              hipStream_t stream){
  const void* x     = d_in[0];
  const int*  ei    = (const int*)d_in[1];
  const void* query = d_in[2];
  const void* W1    = d_in[3];
  const void* as1   = d_in[4];
  const void* ad1   = d_in[5];
  const void* b1    = d_in[6];
  const void* W2    = d_in[7];
  const void* as2   = d_in[8];
  const void* ad2   = d_in[9];
  const void* b2    = d_in[10];
  const void* Wc    = d_in[11];
  const void* bc    = d_in[12];

  int N = in_sizes[0] / 256;
  int E = in_sizes[1] / 2;
  int Q = in_sizes[2] / 256;
  int Et = E + N;
  int NB = (N + 255) / 256;

  char* p = (char*)d_ws;
  auto alloc = [&](size_t bytes)->char*{
    char* r = p; p += (bytes + 255) & ~(size_t)255; return r;
  };
  int*  flags    = (int*) alloc(256);
  u16*  bufA     = (u16*) alloc((size_t)N*256*2);
  u16*  bufB     = (u16*) alloc((size_t)N*256*2);
  float* es      = (float*)alloc((size_t)N*4*4);
  float* ed      = (float*)alloc((size_t)N*4*4);
  int*  deg      = (int*)  alloc((size_t)N*4);
  int*  offs     = (int*)  alloc((size_t)(N+1)*4);
  int*  cursor   = (int*)  alloc((size_t)N*4);
  int*  csr_boff = (int*)  alloc((size_t)Et*4);
  int*  bsum     = (int*)  alloc((size_t)(NB+1)*4);
  int*  bpre     = (int*)  alloc((size_t)(NB+1)*4);
  u16*  BT1      = (u16*)  alloc(256*256*2);
  u16*  BT2      = (u16*)  alloc(256*256*2);
  float* qp      = (float*)alloc(64*4);

  const int thr = 256;
  detect_kernel<<<1, 256, 0, stream>>>((const u32*)x, ei, flags);

  hipMemsetAsync(deg, 0, (size_t)N*4, stream);
  count_kernel  <<<(Et + thr-1)/thr, thr, 0, stream>>>(ei, E, N, deg, flags);
  scan1_kernel  <<<NB, 256, 0, stream>>>(deg, offs, bsum, N);
  scan2_kernel  <<<1, 1024, 0, stream>>>(bsum, bpre, NB);
  scan3_kernel  <<<NB, 256, 0, stream>>>(offs, cursor, bpre, N, NB);
  scatter_kernel<<<(Et + thr-1)/thr, thr, 0, stream>>>(ei, E, N, cursor, csr_boff, flags);

  prep_kernel<<<33, 256, 0, stream>>>(W1, W2, BT1, BT2, query, Wc, bc, qp, Q, flags);

  int gblocks = (N + 63)/64;
  dim3 ngrid((N + 3)/4);

  // ---- layer 1 ----
  gemm_mfma <<<gblocks, 256, 0, stream>>>(x, BT1, bufA, N, 1, flags, es, ed, as1, ad1);
  agg_kernel<<<ngrid, 256, 0, stream>>>(bufA, csr_boff, offs, es, ed, N, b1, bufB, 1, 0,
                                        flags, Wc, qp, Q);
  // ---- layer 2 ----
  gemm_mfma <<<gblocks, 256, 0, stream>>>(bufB, BT2, bufA, N, 0, flags, es, ed, as2, ad2);
  agg_kernel<<<ngrid, 256, 0, stream>>>(bufA, csr_boff, offs, es, ed, N, b2, d_out, 0, 1,
                                        flags, Wc, qp, Q);
}

// Round 14
// 348.387 us; speedup vs baseline: 1.0094x; 1.0094x over previous
//
#include <hip/hip_runtime.h>

typedef unsigned short u16;
typedef unsigned int   u32;
typedef __attribute__((ext_vector_type(8))) short short8v;
typedef __attribute__((ext_vector_type(8))) unsigned short us8;
typedef __attribute__((ext_vector_type(4))) float f32x4;

static __device__ __forceinline__ float bf2f(u16 u){ union{u32 i; float f;} v; v.i=(u32)u<<16; return v.f; }
static __device__ __forceinline__ u16 f2bf(float f){ union{float f; u32 i;} u; u.f=f; u32 r=u.i+0x7FFFu+((u.i>>16)&1u); return (u16)(r>>16); }
// HW packed f32->bf16 (RNE), 1 inst per pair [guide m240: no builtin on gfx950]
static __device__ __forceinline__ u32 cvtpk(float lo, float hi){
  u32 r; asm("v_cvt_pk_bf16_f32 %0, %1, %2" : "=v"(r) : "v"(lo), "v"(hi)); return r;
}

static __device__ __forceinline__ float ld1(const void* p, size_t i, int f32){
  return f32 ? ((const float*)p)[i] : bf2f(((const u16*)p)[i]);
}
static __device__ __forceinline__ float4 ld4(const void* p, size_t i, int f32){
  if (f32) return *((const float4*)((const float*)p + i));
  ushort4 v = *((const ushort4*)((const u16*)p + i));
  return make_float4(bf2f(v.x), bf2f(v.y), bf2f(v.z), bf2f(v.w));
}
static __device__ __forceinline__ void st4(void* p, size_t i, float4 v, int f32){
  if (f32) *((float4*)((float*)p + i)) = v;
  else { ushort4 o; o.x=f2bf(v.x); o.y=f2bf(v.y); o.z=f2bf(v.z); o.w=f2bf(v.w); *((ushort4*)((u16*)p + i)) = o; }
}
static __device__ __forceinline__ void st1(void* p, size_t i, float v, int f32){
  if (f32) ((float*)p)[i] = v; else ((u16*)p)[i] = f2bf(v);
}
static __device__ __forceinline__ int lde(const int* ei, size_t i, int i64){
  return i64 ? ei[2*i] : ei[i];
}
static __device__ __forceinline__ int clampi(int v, int lo, int hi){ return v<lo?lo:(v>hi?hi:v); }

// ---------------- runtime dtype detection ----------------
__global__ void detect_kernel(const u32* __restrict__ x, const int* __restrict__ ei,
                              int* __restrict__ flags){
  __shared__ int cnt[2];
  int t = threadIdx.x;
  if (t < 2) cnt[t] = 0;
  __syncthreads();
  int good = 0;
  for (int i = t; i < 4096; i += 256){
    u32 e = (x[i] >> 7) & 0xFFu;
    if (e >= 90u && e <= 150u) good++;
  }
  atomicAdd(&cnt[0], good);
  int nzodd = 0;
  for (int i = t; i < 2048; i += 256){
    if (ei[2*i+1] != 0) nzodd++;
  }
  atomicAdd(&cnt[1], nzodd);
  __syncthreads();
  if (t == 0){
    flags[0] = (cnt[0] < 2867) ? 1 : 0;
    flags[1] = (cnt[1] == 0) ? 1 : 0;
  }
}

// ---------------- convert x (fp32 path only) to bf16, fully coalesced ----------------
__global__ __launch_bounds__(256) void convx_kernel(const void* __restrict__ x,
    u16* __restrict__ out, long total, const int* __restrict__ flags){
  if (!flags[0]) return;
  long i = ((long)blockIdx.x*256 + threadIdx.x) * 8;
  if (i >= total) return;
  const float* xf = (const float*)x + i;
  float4 v0 = *(const float4*)xf, v1 = *(const float4*)(xf+4);
  union{ u32 w[4]; us8 v; } pk;
  pk.w[0] = cvtpk(v0.x, v0.y); pk.w[1] = cvtpk(v0.z, v0.w);
  pk.w[2] = cvtpk(v1.x, v1.y); pk.w[3] = cvtpk(v1.z, v1.w);
  *(us8*)(out + i) = pk.v;
}

// ---------------- CSR build (separate small kernels; csr stores src*512) ----------------
__global__ void count_kernel(const int* __restrict__ ei, int E, int N,
                             int* __restrict__ deg, const int* __restrict__ flags){
  int i64 = flags[1];
  int i = blockIdx.x*blockDim.x + threadIdx.x;
  int Et = E + N;
  if (i < Et){
    int d = (i < E) ? clampi(lde(ei, (size_t)E + i, i64), 0, N-1) : (i - E);
    atomicAdd(&deg[d], 1);
  }
}

__global__ __launch_bounds__(256) void scan1_kernel(const int* __restrict__ deg,
    int* __restrict__ offs, int* __restrict__ bsum, int N){
  __shared__ int sm[256];
  int t = threadIdx.x;
  int i = blockIdx.x*256 + t;
  int v = (i < N) ? deg[i] : 0;
  sm[t] = v; __syncthreads();
  #pragma unroll
  for (int off = 1; off < 256; off <<= 1){
    int u = (t >= off) ? sm[t-off] : 0;
    __syncthreads();
    sm[t] += u;
    __syncthreads();
  }
  if (i < N) offs[i] = sm[t] - v;
  if (t == 255) bsum[blockIdx.x] = sm[255];
}

__global__ __launch_bounds__(1024) void scan2_kernel(const int* __restrict__ bsum,
    int* __restrict__ bpre, int NB){
  __shared__ int sm[1024];
  int t = threadIdx.x;
  int v = (t < NB) ? bsum[t] : 0;
  sm[t] = v; __syncthreads();
  #pragma unroll
  for (int off = 1; off < 1024; off <<= 1){
    int u = (t >= off) ? sm[t-off] : 0;
    __syncthreads();
    sm[t] += u;
    __syncthreads();
  }
  if (t < NB) bpre[t] = sm[t] - v;
  if (t == 1023) bpre[NB] = sm[1023];
}

__global__ __launch_bounds__(256) void scan3_kernel(int* __restrict__ offs,
    int* __restrict__ cursor, const int* __restrict__ bpre, int N, int NB){
  int i = blockIdx.x*256 + threadIdx.x;
  if (i < N){
    int v = offs[i] + bpre[blockIdx.x];
    offs[i] = v; cursor[i] = v;
  }
  if (i == 0) offs[N] = bpre[NB];
}

__global__ void scatter_kernel(const int* __restrict__ ei, int E, int N,
    int* __restrict__ cursor, int* __restrict__ csr_boff, const int* __restrict__ flags){
  int i64 = flags[1];
  int i = blockIdx.x*blockDim.x + threadIdx.x;
  int Et = E + N;
  if (i < Et){
    int s, d;
    if (i < E){
      s = clampi(lde(ei, i, i64), 0, N-1);
      d = clampi(lde(ei, (size_t)E + i, i64), 0, N-1);
    } else { s = i - E; d = s; }
    int p = atomicAdd(&cursor[d], 1);
    csr_boff[p] = s * 512;
  }
}

// ---------------- prep: B transposes (32 blocks) + qpart (block 32) ----------------
__global__ __launch_bounds__(256) void prep_kernel(const void* __restrict__ B1,
    const void* __restrict__ B2, u16* __restrict__ BT1, u16* __restrict__ BT2,
    const void* __restrict__ query, const void* __restrict__ Wc, const void* __restrict__ bc,
    float* __restrict__ qp, int Q, const int* __restrict__ flags){
  int f32 = flags[0];
  int bid = blockIdx.x;
  if (bid < 32){
    const void* B = (bid >= 16) ? B2 : B1;
    u16* BT = (bid >= 16) ? BT2 : BT1;
    int rem = bid & 15;
    int k0 = (rem >> 2)*64, c0 = (rem & 3)*64;
    __shared__ u16 tile[64][65];
    int r0 = threadIdx.x >> 6, c = threadIdx.x & 63;
    for (int r = r0; r < 64; r += 4)
      tile[r][c] = f32 ? f2bf(((const float*)B)[(size_t)(k0+r)*256 + c0 + c])
                       : ((const u16*)B)[(size_t)(k0+r)*256 + c0 + c];
    __syncthreads();
    for (int j = r0; j < 64; j += 4)
      BT[(size_t)(c0+j)*256 + k0 + c] = tile[c][j];
  } else {
    int q = threadIdx.x >> 5, ln = threadIdx.x & 31;
    if (q >= Q) return;
    float s = 0.f;
    for (int j = ln; j < 256; j += 32) s += ld1(query, q*256 + j, f32) * ld1(Wc, j, f32);
    #pragma unroll
    for (int off = 16; off; off >>= 1) s += __shfl_down(s, off, 32);
    if (ln == 0) qp[q] = s + ld1(bc, 0, f32);
  }
}

// ---------------- LDS-free, barrier-free MFMA GEMM (bf16 A only) ----------------
// Block = 4 waves; wave = 64 rows x 64 cols (wave wn == head wn).
// A selected device-side: A0 if input already bf16, else pre-converted A1.
__global__ __launch_bounds__(256, 4) void gemm_mfma(const u16* __restrict__ A0,
    const u16* __restrict__ A1, const u16* __restrict__ BT, u16* __restrict__ C,
    int M, int aIsInput, const int* __restrict__ flags, float* __restrict__ es,
    float* __restrict__ ed, const void* __restrict__ a_src, const void* __restrict__ a_dst){
  const u16* A16 = (aIsInput && flags[0]) ? A1 : A0;
  int f32 = flags[0];
  int tid = threadIdx.x;
  int wn = tid >> 6, lane = tid & 63;
  int l15 = lane & 15, l4 = lane >> 4;
  int row0 = blockIdx.x * 64;
  int arow[4];
  #pragma unroll
  for (int mi = 0; mi < 4; mi++)
    arow[mi] = min(row0 + mi*16 + l15, M-1);
  const u16* Bb = BT + (size_t)(wn*64 + l15)*256 + 8*l4;
  f32x4 acc[4][4] = {};
  #pragma unroll
  for (int k0 = 0; k0 < 256; k0 += 32){
    short8v a[4], b[4];
    #pragma unroll
    for (int mi = 0; mi < 4; mi++)
      a[mi] = *(const short8v*)(A16 + (size_t)arow[mi]*256 + k0 + 8*l4);
    #pragma unroll
    for (int ni = 0; ni < 4; ni++)
      b[ni] = *(const short8v*)(Bb + (size_t)ni*16*256 + k0);
    #pragma unroll
    for (int mi = 0; mi < 4; mi++)
      #pragma unroll
      for (int ni = 0; ni < 4; ni++)
        acc[mi][ni] = __builtin_amdgcn_mfma_f32_16x16x32_bf16(a[mi], b[ni], acc[mi][ni], 0, 0, 0);
  }
  // C store (verified mapping: col=l15, row=l4*4+r within 16x16)
  #pragma unroll
  for (int mi = 0; mi < 4; mi++){
    #pragma unroll
    for (int ni = 0; ni < 4; ni++){
      #pragma unroll
      for (int r = 0; r < 4; r++){
        int row = row0 + mi*16 + l4*4 + r;
        int col = wn*64 + ni*16 + l15;
        if (row < M) C[(size_t)row*256 + col] = f2bf(acc[mi][ni][r]);
      }
    }
  }
  // fused es/ed: wave wn == head wn; reduce over this wave's 64 cols
  float as_[4], ad_[4];
  #pragma unroll
  for (int ni = 0; ni < 4; ni++){
    as_[ni] = ld1(a_src, wn*64 + ni*16 + l15, f32);
    ad_[ni] = ld1(a_dst, wn*64 + ni*16 + l15, f32);
  }
  #pragma unroll
  for (int mi = 0; mi < 4; mi++){
    #pragma unroll
    for (int r = 0; r < 4; r++){
      float pe = acc[mi][0][r]*as_[0] + acc[mi][1][r]*as_[1]
               + acc[mi][2][r]*as_[2] + acc[mi][3][r]*as_[3];
      float pd = acc[mi][0][r]*ad_[0] + acc[mi][1][r]*ad_[1]
               + acc[mi][2][r]*ad_[2] + acc[mi][3][r]*ad_[3];
      #pragma unroll
      for (int off = 1; off < 16; off <<= 1){
        pe += __shfl_xor(pe, off, 64);
        pd += __shfl_xor(pd, off, 64);
      }
      if (l15 == 0){
        int row = row0 + mi*16 + l4*4 + r;
        if (row < M){
          es[(size_t)row*4 + wn] = pe;
          ed[(size_t)row*4 + wn] = pd;
        }
      }
    }
  }
}

// ---------------- fused aggregation (byte-offset CSR) + nscore epilogue ----------------
__global__ __launch_bounds__(256) void agg_kernel(const u16* __restrict__ h,
    const int* __restrict__ csr_boff, const int* __restrict__ offs,
    const float* __restrict__ es, const float* __restrict__ ed, int N,
    const void* __restrict__ bias, void* __restrict__ out, int do_relu, int outIsOutput,
    const int* __restrict__ flags, const void* __restrict__ Wc,
    const float* __restrict__ qp, int Q){
  int f32in = flags[0];
  int of32  = outIsOutput ? flags[0] : 0;
  int ln = threadIdx.x & 63;
  int n = blockIdx.x*4 + (threadIdx.x >> 6);
  if (n >= N) return;
  int beg = offs[n], end = offs[n+1];
  int hd = ln >> 4, c0 = ln*4;
  int hd4 = hd*4;
  size_t coff = (size_t)c0*2;
  const char* hbase = (const char*)h;
  const char* ebase = (const char*)es;
  float edn = ed[(size_t)n*4 + hd];
  float a0=0.f, a1=0.f, a2=0.f, a3=0.f, ws=0.f;
  int i = beg;
  for (; i + 8 <= end; i += 8){
    int bo[8]; float x[8]; ushort4 hv[8];
    #pragma unroll
    for (int j = 0; j < 8; j++) bo[j] = csr_boff[i+j];
    #pragma unroll
    for (int j = 0; j < 8; j++) x[j] = *(const float*)(ebase + (bo[j] >> 5) + hd4);
    #pragma unroll
    for (int j = 0; j < 8; j++) hv[j] = *(const ushort4*)(hbase + bo[j] + coff);
    #pragma unroll
    for (int j = 0; j < 8; j++){
      float t = x[j] + edn; t = (t > 0.f) ? t : 0.2f*t; t = fminf(t, 60.f);
      float w = __expf(t);
      a0 += w*bf2f(hv[j].x); a1 += w*bf2f(hv[j].y);
      a2 += w*bf2f(hv[j].z); a3 += w*bf2f(hv[j].w);
      ws += w;
    }
  }
  for (; i + 4 <= end; i += 4){
    int bo[4]; float x[4]; ushort4 hv[4];
    #pragma unroll
    for (int j = 0; j < 4; j++) bo[j] = csr_boff[i+j];
    #pragma unroll
    for (int j = 0; j < 4; j++) x[j] = *(const float*)(ebase + (bo[j] >> 5) + hd4);
    #pragma unroll
    for (int j = 0; j < 4; j++) hv[j] = *(const ushort4*)(hbase + bo[j] + coff);
    #pragma unroll
    for (int j = 0; j < 4; j++){
      float t = x[j] + edn; t = (t > 0.f) ? t : 0.2f*t; t = fminf(t, 60.f);
      float w = __expf(t);
      a0 += w*bf2f(hv[j].x); a1 += w*bf2f(hv[j].y);
      a2 += w*bf2f(hv[j].z); a3 += w*bf2f(hv[j].w);
      ws += w;
    }
  }
  for (; i < end; i++){
    int bo = csr_boff[i];
    float t = *(const float*)(ebase + (bo >> 5) + hd4) + edn;
    t = (t > 0.f) ? t : 0.2f*t; t = fminf(t, 60.f);
    float w = __expf(t);
    ushort4 hv = *(const ushort4*)(hbase + bo + coff);
    a0 += w*bf2f(hv.x); a1 += w*bf2f(hv.y);
    a2 += w*bf2f(hv.z); a3 += w*bf2f(hv.w);
    ws += w;
  }
  float inv = 1.f / (ws + 1e-16f);
  float4 bv = ld4(bias, c0, f32in);
  float4 ov = make_float4(a0*inv + bv.x, a1*inv + bv.y, a2*inv + bv.z, a3*inv + bv.w);
  if (do_relu){
    ov.x = fmaxf(ov.x, 0.f); ov.y = fmaxf(ov.y, 0.f);
    ov.z = fmaxf(ov.z, 0.f); ov.w = fmaxf(ov.w, 0.f);
  }
  st4(out, (size_t)n*256 + c0, ov, of32);
  if (outIsOutput){
    float4 wc4 = ld4(Wc, 256 + c0, f32in);
    float v = ov.x*wc4.x + ov.y*wc4.y + ov.z*wc4.z + ov.w*wc4.w;
    #pragma unroll
    for (int off = 1; off < 64; off <<= 1) v += __shfl_xor(v, off, 64);
    if (ln < Q) st1(out, (size_t)N*256 + (size_t)ln*N + n, qp[ln] + v, of32);
  }
}

extern "C" void kernel_launch(void* const* d_in, const int* in_sizes, int n_in,
                              void* d_out, int out_size, void* d_ws, size_t ws_size,
                              hipStream_t stream){
  const void* x     = d_in[0];
  const int*  ei    = (const int*)d_in[1];
  const void* query = d_in[2];
  const void* W1    = d_in[3];
  const void* as1   = d_in[4];
  const void* ad1   = d_in[5];
  const void* b1    = d_in[6];
  const void* W2    = d_in[7];
  const void* as2   = d_in[8];
  const void* ad2   = d_in[9];
  const void* b2    = d_in[10];
  const void* Wc    = d_in[11];
  const void* bc    = d_in[12];

  int N = in_sizes[0] / 256;
  int E = in_sizes[1] / 2;
  int Q = in_sizes[2] / 256;
  int Et = E + N;
  int NB = (N + 255) / 256;

  char* p = (char*)d_ws;
  auto alloc = [&](size_t bytes)->char*{
    char* r = p; p += (bytes + 255) & ~(size_t)255; return r;
  };
  int*  flags    = (int*) alloc(256);
  u16*  bufA     = (u16*) alloc((size_t)N*256*2);
  u16*  bufB     = (u16*) alloc((size_t)N*256*2);
  u16*  xb       = (u16*) alloc((size_t)N*256*2);   // bf16 copy of x (fp32 path)
  float* es      = (float*)alloc((size_t)N*4*4);
  float* ed      = (float*)alloc((size_t)N*4*4);
  int*  deg      = (int*)  alloc((size_t)N*4);
  int*  offs     = (int*)  alloc((size_t)(N+1)*4);
  int*  cursor   = (int*)  alloc((size_t)N*4);
  int*  csr_boff = (int*)  alloc((size_t)Et*4);
  int*  bsum     = (int*)  alloc((size_t)(NB+1)*4);
  int*  bpre     = (int*)  alloc((size_t)(NB+1)*4);
  u16*  BT1      = (u16*)  alloc(256*256*2);
  u16*  BT2      = (u16*)  alloc(256*256*2);
  float* qp      = (float*)alloc(64*4);

  const int thr = 256;
  detect_kernel<<<1, 256, 0, stream>>>((const u32*)x, ei, flags);

  hipMemsetAsync(deg, 0, (size_t)N*4, stream);
  count_kernel  <<<(Et + thr-1)/thr, thr, 0, stream>>>(ei, E, N, deg, flags);
  scan1_kernel  <<<NB, 256, 0, stream>>>(deg, offs, bsum, N);
  scan2_kernel  <<<1, 1024, 0, stream>>>(bsum, bpre, NB);
  scan3_kernel  <<<NB, 256, 0, stream>>>(offs, cursor, bpre, N, NB);
  scatter_kernel<<<(Et + thr-1)/thr, thr, 0, stream>>>(ei, E, N, cursor, csr_boff, flags);

  prep_kernel<<<33, 256, 0, stream>>>(W1, W2, BT1, BT2, query, Wc, bc, qp, Q, flags);

  long xtotal = (long)N*256;
  int cxblocks = (int)((xtotal/8 + 255) / 256);
  convx_kernel<<<cxblocks, 256, 0, stream>>>(x, xb, xtotal, flags);

  int gblocks = (N + 63)/64;
  dim3 ngrid((N + 3)/4);

  // ---- layer 1 ----
  gemm_mfma <<<gblocks, 256, 0, stream>>>((const u16*)x, xb, BT1, bufA, N, 1, flags,
                                          es, ed, as1, ad1);
  agg_kernel<<<ngrid, 256, 0, stream>>>(bufA, csr_boff, offs, es, ed, N, b1, bufB, 1, 0,
                                        flags, Wc, qp, Q);
  // ---- layer 2 ----
  gemm_mfma <<<gblocks, 256, 0, stream>>>(bufB, bufB, BT2, bufA, N, 0, flags,
                                          es, ed, as2, ad2);
  agg_kernel<<<ngrid, 256, 0, stream>>>(bufA, csr_boff, offs, es, ed, N, b2, d_out, 0, 1,
                                        flags, Wc, qp, Q);
}

// Round 15
// 312.686 us; speedup vs baseline: 1.1247x; 1.1142x over previous
//
#include <hip/hip_runtime.h>

typedef unsigned short u16;
typedef unsigned int   u32;
typedef __attribute__((ext_vector_type(8))) short short8v;
typedef __attribute__((ext_vector_type(8))) unsigned short us8;
typedef __attribute__((ext_vector_type(4))) float f32x4;

static __device__ __forceinline__ float bf2f(u16 u){ union{u32 i; float f;} v; v.i=(u32)u<<16; return v.f; }
static __device__ __forceinline__ u16 f2bf(float f){ union{float f; u32 i;} u; u.f=f; u32 r=u.i+0x7FFFu+((u.i>>16)&1u); return (u16)(r>>16); }
// HW packed f32->bf16 (RNE) [guide m240: no builtin on gfx950]
static __device__ __forceinline__ u32 cvtpk(float lo, float hi){
  u32 r; asm("v_cvt_pk_bf16_f32 %0, %1, %2" : "=v"(r) : "v"(lo), "v"(hi)); return r;
}
// async global->LDS, 16B per lane: dst is wave-uniform base + lane*16 [guide m97]
static __device__ __forceinline__ void gload16(const u16* g, u16* l){
  __builtin_amdgcn_global_load_lds(
      (const __attribute__((address_space(1))) u32*)g,
      (__attribute__((address_space(3))) u32*)l, 16, 0, 0);
}

static __device__ __forceinline__ float ld1(const void* p, size_t i, int f32){
  return f32 ? ((const float*)p)[i] : bf2f(((const u16*)p)[i]);
}
static __device__ __forceinline__ float4 ld4(const void* p, size_t i, int f32){
  if (f32) return *((const float4*)((const float*)p + i));
  ushort4 v = *((const ushort4*)((const u16*)p + i));
  return make_float4(bf2f(v.x), bf2f(v.y), bf2f(v.z), bf2f(v.w));
}
static __device__ __forceinline__ void st4(void* p, size_t i, float4 v, int f32){
  if (f32) *((float4*)((float*)p + i)) = v;
  else { ushort4 o; o.x=f2bf(v.x); o.y=f2bf(v.y); o.z=f2bf(v.z); o.w=f2bf(v.w); *((ushort4*)((u16*)p + i)) = o; }
}
static __device__ __forceinline__ void st1(void* p, size_t i, float v, int f32){
  if (f32) ((float*)p)[i] = v; else ((u16*)p)[i] = f2bf(v);
}
static __device__ __forceinline__ int lde(const int* ei, size_t i, int i64){
  return i64 ? ei[2*i] : ei[i];
}
static __device__ __forceinline__ int clampi(int v, int lo, int hi){ return v<lo?lo:(v>hi?hi:v); }

// ---------------- runtime dtype detection ----------------
__global__ void detect_kernel(const u32* __restrict__ x, const int* __restrict__ ei,
                              int* __restrict__ flags){
  __shared__ int cnt[2];
  int t = threadIdx.x;
  if (t < 2) cnt[t] = 0;
  __syncthreads();
  int good = 0;
  for (int i = t; i < 4096; i += 256){
    u32 e = (x[i] >> 7) & 0xFFu;
    if (e >= 90u && e <= 150u) good++;
  }
  atomicAdd(&cnt[0], good);
  int nzodd = 0;
  for (int i = t; i < 2048; i += 256){
    if (ei[2*i+1] != 0) nzodd++;
  }
  atomicAdd(&cnt[1], nzodd);
  __syncthreads();
  if (t == 0){
    flags[0] = (cnt[0] < 2867) ? 1 : 0;
    flags[1] = (cnt[1] == 0) ? 1 : 0;
  }
}

// ---------------- convert x (fp32 path only) to bf16, fully coalesced ----------------
__global__ __launch_bounds__(256) void convx_kernel(const void* __restrict__ x,
    u16* __restrict__ out, long total, const int* __restrict__ flags){
  if (!flags[0]) return;
  long i = ((long)blockIdx.x*256 + threadIdx.x) * 8;
  if (i >= total) return;
  const float* xf = (const float*)x + i;
  float4 v0 = *(const float4*)xf, v1 = *(const float4*)(xf+4);
  union{ u32 w[4]; us8 v; } pk;
  pk.w[0] = cvtpk(v0.x, v0.y); pk.w[1] = cvtpk(v0.z, v0.w);
  pk.w[2] = cvtpk(v1.x, v1.y); pk.w[3] = cvtpk(v1.z, v1.w);
  *(us8*)(out + i) = pk.v;
}

// ---------------- CSR build (separate small kernels; csr stores src*512) ----------------
__global__ void count_kernel(const int* __restrict__ ei, int E, int N,
                             int* __restrict__ deg, const int* __restrict__ flags){
  int i64 = flags[1];
  int i = blockIdx.x*blockDim.x + threadIdx.x;
  int Et = E + N;
  if (i < Et){
    int d = (i < E) ? clampi(lde(ei, (size_t)E + i, i64), 0, N-1) : (i - E);
    atomicAdd(&deg[d], 1);
  }
}

__global__ __launch_bounds__(256) void scan1_kernel(const int* __restrict__ deg,
    int* __restrict__ offs, int* __restrict__ bsum, int N){
  __shared__ int sm[256];
  int t = threadIdx.x;
  int i = blockIdx.x*256 + t;
  int v = (i < N) ? deg[i] : 0;
  sm[t] = v; __syncthreads();
  #pragma unroll
  for (int off = 1; off < 256; off <<= 1){
    int u = (t >= off) ? sm[t-off] : 0;
    __syncthreads();
    sm[t] += u;
    __syncthreads();
  }
  if (i < N) offs[i] = sm[t] - v;
  if (t == 255) bsum[blockIdx.x] = sm[255];
}

__global__ __launch_bounds__(1024) void scan2_kernel(const int* __restrict__ bsum,
    int* __restrict__ bpre, int NB){
  __shared__ int sm[1024];
  int t = threadIdx.x;
  int v = (t < NB) ? bsum[t] : 0;
  sm[t] = v; __syncthreads();
  #pragma unroll
  for (int off = 1; off < 1024; off <<= 1){
    int u = (t >= off) ? sm[t-off] : 0;
    __syncthreads();
    sm[t] += u;
    __syncthreads();
  }
  if (t < NB) bpre[t] = sm[t] - v;
  if (t == 1023) bpre[NB] = sm[1023];
}

__global__ __launch_bounds__(256) void scan3_kernel(int* __restrict__ offs,
    int* __restrict__ cursor, const int* __restrict__ bpre, int N, int NB){
  int i = blockIdx.x*256 + threadIdx.x;
  if (i < N){
    int v = offs[i] + bpre[blockIdx.x];
    offs[i] = v; cursor[i] = v;
  }
  if (i == 0) offs[N] = bpre[NB];
}

__global__ void scatter_kernel(const int* __restrict__ ei, int E, int N,
    int* __restrict__ cursor, int* __restrict__ csr_boff, const int* __restrict__ flags){
  int i64 = flags[1];
  int i = blockIdx.x*blockDim.x + threadIdx.x;
  int Et = E + N;
  if (i < Et){
    int s, d;
    if (i < E){
      s = clampi(lde(ei, i, i64), 0, N-1);
      d = clampi(lde(ei, (size_t)E + i, i64), 0, N-1);
    } else { s = i - E; d = s; }
    int p = atomicAdd(&cursor[d], 1);
    csr_boff[p] = s * 512;
  }
}

// ---------------- prep: B transposes (32 blocks) + qpart (block 32) ----------------
__global__ __launch_bounds__(256) void prep_kernel(const void* __restrict__ B1,
    const void* __restrict__ B2, u16* __restrict__ BT1, u16* __restrict__ BT2,
    const void* __restrict__ query, const void* __restrict__ Wc, const void* __restrict__ bc,
    float* __restrict__ qp, int Q, const int* __restrict__ flags){
  int f32 = flags[0];
  int bid = blockIdx.x;
  if (bid < 32){
    const void* B = (bid >= 16) ? B2 : B1;
    u16* BT = (bid >= 16) ? BT2 : BT1;
    int rem = bid & 15;
    int k0 = (rem >> 2)*64, c0 = (rem & 3)*64;
    __shared__ u16 tile[64][65];
    int r0 = threadIdx.x >> 6, c = threadIdx.x & 63;
    for (int r = r0; r < 64; r += 4)
      tile[r][c] = f32 ? f2bf(((const float*)B)[(size_t)(k0+r)*256 + c0 + c])
                       : ((const u16*)B)[(size_t)(k0+r)*256 + c0 + c];
    __syncthreads();
    for (int j = r0; j < 64; j += 4)
      BT[(size_t)(c0+j)*256 + k0 + c] = tile[c][j];
  } else {
    int q = threadIdx.x >> 5, ln = threadIdx.x & 31;
    if (q >= Q) return;
    float s = 0.f;
    for (int j = ln; j < 256; j += 32) s += ld1(query, q*256 + j, f32) * ld1(Wc, j, f32);
    #pragma unroll
    for (int off = 16; off; off >>= 1) s += __shfl_down(s, off, 32);
    if (ln == 0) qp[q] = s + ld1(bc, 0, f32);
  }
}

// ---------------- MFMA GEMM: 512 thr, 128x256 tile, global_load_lds staging ----------------
// Linear LDS + both-sides XOR chunk swizzle (phys = l4 ^ ((row>>1)&3)): 2-way banks (free).
// A always bf16 (xb pre-converted). Wave wn == head wn -> in-wave fused es/ed.
__global__ __launch_bounds__(512, 4) void gemm_mfma(const u16* __restrict__ A0,
    const u16* __restrict__ A1, const u16* __restrict__ BT, u16* __restrict__ C,
    int M, int aIsInput, const int* __restrict__ flags, float* __restrict__ es,
    float* __restrict__ ed, const void* __restrict__ a_src, const void* __restrict__ a_dst){
  const u16* A16 = (aIsInput && flags[0]) ? A1 : A0;
  int f32 = flags[0];
  __shared__ __align__(16) u16 As[128*32];   // linear: row*32 + chunk*8
  __shared__ __align__(16) u16 Bs[256*32];   // linear: col*32 + chunk*8
  int tid = threadIdx.x;
  int wave = tid >> 6, lane = tid & 63;
  int wm = wave >> 2, wn = wave & 3;
  int l15 = lane & 15, l4 = lane >> 4;
  int row0 = blockIdx.x * 128;
  // A staging: slot = tid; covers (row = tid>>2, pchunk = tid&3)
  int arow_s = tid >> 2, apch = tid & 3;
  int agr = min(row0 + arow_s, M-1);
  const u16* aSrc = A16 + (size_t)agr*256 + (apch ^ ((arow_s >> 1) & 3))*8;
  u16* aDst = &As[(size_t)wave*512];                      // wave-uniform
  // B staging: two slots per thread: sb_j = (wave*2+j)*64 + lane
  int sb0 = (wave*2+0)*64 + lane, sb1 = (wave*2+1)*64 + lane;
  int bc0 = sb0 >> 2, bp0 = sb0 & 3;
  int bc1 = sb1 >> 2, bp1 = sb1 & 3;
  const u16* bSrc0 = BT + (size_t)bc0*256 + (bp0 ^ ((bc0 >> 1) & 3))*8;
  const u16* bSrc1 = BT + (size_t)bc1*256 + (bp1 ^ ((bc1 >> 1) & 3))*8;
  u16* bDst0 = &Bs[(size_t)(wave*2+0)*512];
  u16* bDst1 = &Bs[(size_t)(wave*2+1)*512];
  f32x4 acc[4][4] = {};
  for (int k0 = 0; k0 < 256; k0 += 32){
    __syncthreads();                 // prev compute done reading LDS
    gload16(aSrc + k0, aDst);
    gload16(bSrc0 + k0, bDst0);
    gload16(bSrc1 + k0, bDst1);
    __syncthreads();                 // compiler drains vmcnt before barrier
    short8v a[4], b[4];
    #pragma unroll
    for (int mi = 0; mi < 4; mi++){
      int row = wm*64 + mi*16 + l15;
      a[mi] = *(const short8v*)&As[row*32 + (l4 ^ ((row >> 1) & 3))*8];
    }
    #pragma unroll
    for (int ni = 0; ni < 4; ni++){
      int col = wn*64 + ni*16 + l15;
      b[ni] = *(const short8v*)&Bs[col*32 + (l4 ^ ((col >> 1) & 3))*8];
    }
    #pragma unroll
    for (int mi = 0; mi < 4; mi++)
      #pragma unroll
      for (int ni = 0; ni < 4; ni++)
        acc[mi][ni] = __builtin_amdgcn_mfma_f32_16x16x32_bf16(a[mi], b[ni], acc[mi][ni], 0, 0, 0);
  }
  // C store (verified mapping: col=l15, row=l4*4+r within 16x16)
  #pragma unroll
  for (int mi = 0; mi < 4; mi++){
    #pragma unroll
    for (int ni = 0; ni < 4; ni++){
      #pragma unroll
      for (int r = 0; r < 4; r++){
        int row = row0 + wm*64 + mi*16 + l4*4 + r;
        int col = wn*64 + ni*16 + l15;
        if (row < M) C[(size_t)row*256 + col] = f2bf(acc[mi][ni][r]);
      }
    }
  }
  // fused es/ed: wave wn == head wn
  float as_[4], ad_[4];
  #pragma unroll
  for (int ni = 0; ni < 4; ni++){
    as_[ni] = ld1(a_src, wn*64 + ni*16 + l15, f32);
    ad_[ni] = ld1(a_dst, wn*64 + ni*16 + l15, f32);
  }
  #pragma unroll
  for (int mi = 0; mi < 4; mi++){
    #pragma unroll
    for (int r = 0; r < 4; r++){
      float pe = acc[mi][0][r]*as_[0] + acc[mi][1][r]*as_[1]
               + acc[mi][2][r]*as_[2] + acc[mi][3][r]*as_[3];
      float pd = acc[mi][0][r]*ad_[0] + acc[mi][1][r]*ad_[1]
               + acc[mi][2][r]*ad_[2] + acc[mi][3][r]*ad_[3];
      #pragma unroll
      for (int off = 1; off < 16; off <<= 1){
        pe += __shfl_xor(pe, off, 64);
        pd += __shfl_xor(pd, off, 64);
      }
      if (l15 == 0){
        int row = row0 + wm*64 + mi*16 + l4*4 + r;
        if (row < M){
          es[(size_t)row*4 + wn] = pe;
          ed[(size_t)row*4 + wn] = pd;
        }
      }
    }
  }
}

// ---------------- fused aggregation (byte-offset CSR) + nscore epilogue ----------------
__global__ __launch_bounds__(256) void agg_kernel(const u16* __restrict__ h,
    const int* __restrict__ csr_boff, const int* __restrict__ offs,
    const float* __restrict__ es, const float* __restrict__ ed, int N,
    const void* __restrict__ bias, void* __restrict__ out, int do_relu, int outIsOutput,
    const int* __restrict__ flags, const void* __restrict__ Wc,
    const float* __restrict__ qp, int Q){
  int f32in = flags[0];
  int of32  = outIsOutput ? flags[0] : 0;
  int ln = threadIdx.x & 63;
  int n = blockIdx.x*4 + (threadIdx.x >> 6);
  if (n >= N) return;
  int beg = offs[n], end = offs[n+1];
  int hd = ln >> 4, c0 = ln*4;
  int hd4 = hd*4;
  size_t coff = (size_t)c0*2;
  const char* hbase = (const char*)h;
  const char* ebase = (const char*)es;
  float edn = ed[(size_t)n*4 + hd];
  float a0=0.f, a1=0.f, a2=0.f, a3=0.f, ws=0.f;
  int i = beg;
  for (; i + 8 <= end; i += 8){
    int bo[8]; float x[8]; ushort4 hv[8];
    #pragma unroll
    for (int j = 0; j < 8; j++) bo[j] = csr_boff[i+j];
    #pragma unroll
    for (int j = 0; j < 8; j++) x[j] = *(const float*)(ebase + (bo[j] >> 5) + hd4);
    #pragma unroll
    for (int j = 0; j < 8; j++) hv[j] = *(const ushort4*)(hbase + bo[j] + coff);
    #pragma unroll
    for (int j = 0; j < 8; j++){
      float t = x[j] + edn; t = (t > 0.f) ? t : 0.2f*t; t = fminf(t, 60.f);
      float w = __expf(t);
      a0 += w*bf2f(hv[j].x); a1 += w*bf2f(hv[j].y);
      a2 += w*bf2f(hv[j].z); a3 += w*bf2f(hv[j].w);
      ws += w;
    }
  }
  for (; i + 4 <= end; i += 4){
    int bo[4]; float x[4]; ushort4 hv[4];
    #pragma unroll
    for (int j = 0; j < 4; j++) bo[j] = csr_boff[i+j];
    #pragma unroll
    for (int j = 0; j < 4; j++) x[j] = *(const float*)(ebase + (bo[j] >> 5) + hd4);
    #pragma unroll
    for (int j = 0; j < 4; j++) hv[j] = *(const ushort4*)(hbase + bo[j] + coff);
    #pragma unroll
    for (int j = 0; j < 4; j++){
      float t = x[j] + edn; t = (t > 0.f) ? t : 0.2f*t; t = fminf(t, 60.f);
      float w = __expf(t);
      a0 += w*bf2f(hv[j].x); a1 += w*bf2f(hv[j].y);
      a2 += w*bf2f(hv[j].z); a3 += w*bf2f(hv[j].w);
      ws += w;
    }
  }
  for (; i < end; i++){
    int bo = csr_boff[i];
    float t = *(const float*)(ebase + (bo >> 5) + hd4) + edn;
    t = (t > 0.f) ? t : 0.2f*t; t = fminf(t, 60.f);
    float w = __expf(t);
    ushort4 hv = *(const ushort4*)(hbase + bo + coff);
    a0 += w*bf2f(hv.x); a1 += w*bf2f(hv.y);
    a2 += w*bf2f(hv.z); a3 += w*bf2f(hv.w);
    ws += w;
  }
  float inv = 1.f / (ws + 1e-16f);
  float4 bv = ld4(bias, c0, f32in);
  float4 ov = make_float4(a0*inv + bv.x, a1*inv + bv.y, a2*inv + bv.z, a3*inv + bv.w);
  if (do_relu){
    ov.x = fmaxf(ov.x, 0.f); ov.y = fmaxf(ov.y, 0.f);
    ov.z = fmaxf(ov.z, 0.f); ov.w = fmaxf(ov.w, 0.f);
  }
  st4(out, (size_t)n*256 + c0, ov, of32);
  if (outIsOutput){
    float4 wc4 = ld4(Wc, 256 + c0, f32in);
    float v = ov.x*wc4.x + ov.y*wc4.y + ov.z*wc4.z + ov.w*wc4.w;
    #pragma unroll
    for (int off = 1; off < 64; off <<= 1) v += __shfl_xor(v, off, 64);
    if (ln < Q) st1(out, (size_t)N*256 + (size_t)ln*N + n, qp[ln] + v, of32);
  }
}

extern "C" void kernel_launch(void* const* d_in, const int* in_sizes, int n_in,
                              void* d_out, int out_size, void* d_ws, size_t ws_size,
                              hipStream_t stream){
  const void* x     = d_in[0];
  const int*  ei    = (const int*)d_in[1];
  const void* query = d_in[2];
  const void* W1    = d_in[3];
  const void* as1   = d_in[4];
  const void* ad1   = d_in[5];
  const void* b1    = d_in[6];
  const void* W2    = d_in[7];
  const void* as2   = d_in[8];
  const void* ad2   = d_in[9];
  const void* b2    = d_in[10];
  const void* Wc    = d_in[11];
  const void* bc    = d_in[12];

  int N = in_sizes[0] / 256;
  int E = in_sizes[1] / 2;
  int Q = in_sizes[2] / 256;
  int Et = E + N;
  int NB = (N + 255) / 256;

  char* p = (char*)d_ws;
  auto alloc = [&](size_t bytes)->char*{
    char* r = p; p += (bytes + 255) & ~(size_t)255; return r;
  };
  int*  flags    = (int*) alloc(256);
  u16*  bufA     = (u16*) alloc((size_t)N*256*2);
  u16*  bufB     = (u16*) alloc((size_t)N*256*2);
  u16*  xb       = (u16*) alloc((size_t)N*256*2);   // bf16 copy of x (fp32 path)
  float* es      = (float*)alloc((size_t)N*4*4);
  float* ed      = (float*)alloc((size_t)N*4*4);
  int*  deg      = (int*)  alloc((size_t)N*4);
  int*  offs     = (int*)  alloc((size_t)(N+1)*4);
  int*  cursor   = (int*)  alloc((size_t)N*4);
  int*  csr_boff = (int*)  alloc((size_t)Et*4);
  int*  bsum     = (int*)  alloc((size_t)(NB+1)*4);
  int*  bpre     = (int*)  alloc((size_t)(NB+1)*4);
  u16*  BT1      = (u16*)  alloc(256*256*2);
  u16*  BT2      = (u16*)  alloc(256*256*2);
  float* qp      = (float*)alloc(64*4);

  const int thr = 256;
  detect_kernel<<<1, 256, 0, stream>>>((const u32*)x, ei, flags);

  hipMemsetAsync(deg, 0, (size_t)N*4, stream);
  count_kernel  <<<(Et + thr-1)/thr, thr, 0, stream>>>(ei, E, N, deg, flags);
  scan1_kernel  <<<NB, 256, 0, stream>>>(deg, offs, bsum, N);
  scan2_kernel  <<<1, 1024, 0, stream>>>(bsum, bpre, NB);
  scan3_kernel  <<<NB, 256, 0, stream>>>(offs, cursor, bpre, N, NB);
  scatter_kernel<<<(Et + thr-1)/thr, thr, 0, stream>>>(ei, E, N, cursor, csr_boff, flags);

  prep_kernel<<<33, 256, 0, stream>>>(W1, W2, BT1, BT2, query, Wc, bc, qp, Q, flags);

  long xtotal = (long)N*256;
  int cxblocks = (int)((xtotal/8 + 255) / 256);
  convx_kernel<<<cxblocks, 256, 0, stream>>>(x, xb, xtotal, flags);

  int gblocks = (N + 127)/128;
  dim3 ngrid((N + 3)/4);

  // ---- layer 1 ----
  gemm_mfma <<<gblocks, 512, 0, stream>>>((const u16*)x, xb, BT1, bufA, N, 1, flags,
                                          es, ed, as1, ad1);
  agg_kernel<<<ngrid, 256, 0, stream>>>(bufA, csr_boff, offs, es, ed, N, b1, bufB, 1, 0,
                                        flags, Wc, qp, Q);
  // ---- layer 2 ----
  gemm_mfma <<<gblocks, 512, 0, stream>>>(bufB, bufB, BT2, bufA, N, 0, flags,
                                          es, ed, as2, ad2);
  agg_kernel<<<ngrid, 256, 0, stream>>>(bufA, csr_boff, offs, es, ed, N, b2, d_out, 0, 1,
                                        flags, Wc, qp, Q);
}

// Round 16
// 300.734 us; speedup vs baseline: 1.1694x; 1.0397x over previous
//
#include <hip/hip_runtime.h>

typedef unsigned short u16;
typedef unsigned int   u32;
typedef __attribute__((ext_vector_type(8))) short short8v;
typedef __attribute__((ext_vector_type(8))) unsigned short us8;
typedef __attribute__((ext_vector_type(4))) float f32x4;

static __device__ __forceinline__ float bf2f(u16 u){ union{u32 i; float f;} v; v.i=(u32)u<<16; return v.f; }
static __device__ __forceinline__ u16 f2bf(float f){ union{float f; u32 i;} u; u.f=f; u32 r=u.i+0x7FFFu+((u.i>>16)&1u); return (u16)(r>>16); }

static __device__ __forceinline__ float ld1(const void* p, size_t i, int f32){
  return f32 ? ((const float*)p)[i] : bf2f(((const u16*)p)[i]);
}
static __device__ __forceinline__ float4 ld4(const void* p, size_t i, int f32){
  if (f32) return *((const float4*)((const float*)p + i));
  ushort4 v = *((const ushort4*)((const u16*)p + i));
  return make_float4(bf2f(v.x), bf2f(v.y), bf2f(v.z), bf2f(v.w));
}
static __device__ __forceinline__ void st4(void* p, size_t i, float4 v, int f32){
  if (f32) *((float4*)((float*)p + i)) = v;
  else { ushort4 o; o.x=f2bf(v.x); o.y=f2bf(v.y); o.z=f2bf(v.z); o.w=f2bf(v.w); *((ushort4*)((u16*)p + i)) = o; }
}
static __device__ __forceinline__ void st1(void* p, size_t i, float v, int f32){
  if (f32) ((float*)p)[i] = v; else ((u16*)p)[i] = f2bf(v);
}
static __device__ __forceinline__ int lde(const int* ei, size_t i, int i64){
  return i64 ? ei[2*i] : ei[i];
}
static __device__ __forceinline__ int clampi(int v, int lo, int hi){ return v<lo?lo:(v>hi?hi:v); }

// ---------------- detect dtypes (block 0) + zero deg (blocks 1..) ----------------
__global__ void detect_zero_kernel(const u32* __restrict__ x, const int* __restrict__ ei,
                                   int* __restrict__ flags, int* __restrict__ deg, int N){
  if (blockIdx.x != 0){
    int i = (blockIdx.x - 1)*256 + threadIdx.x;
    if (i < N) deg[i] = 0;
    return;
  }
  __shared__ int cnt[2];
  int t = threadIdx.x;
  if (t < 2) cnt[t] = 0;
  __syncthreads();
  int good = 0;
  for (int i = t; i < 4096; i += 256){
    u32 e = (x[i] >> 7) & 0xFFu;
    if (e >= 90u && e <= 150u) good++;
  }
  atomicAdd(&cnt[0], good);
  int nzodd = 0;
  for (int i = t; i < 2048; i += 256){
    if (ei[2*i+1] != 0) nzodd++;
  }
  atomicAdd(&cnt[1], nzodd);
  __syncthreads();
  if (t == 0){
    flags[0] = (cnt[0] < 2867) ? 1 : 0;
    flags[1] = (cnt[1] == 0) ? 1 : 0;
  }
}

// ---------------- CSR build ----------------
__global__ void count_kernel(const int* __restrict__ ei, int E, int N,
                             int* __restrict__ deg, const int* __restrict__ flags){
  int i64 = flags[1];
  int i = blockIdx.x*blockDim.x + threadIdx.x;
  int Et = E + N;
  if (i < Et){
    int d = (i < E) ? clampi(lde(ei, (size_t)E + i, i64), 0, N-1) : (i - E);
    atomicAdd(&deg[d], 1);
  }
}

__global__ __launch_bounds__(256) void scan1_kernel(const int* __restrict__ deg,
    int* __restrict__ offs, int* __restrict__ bsum, int N){
  __shared__ int sm[256];
  int t = threadIdx.x;
  int i = blockIdx.x*256 + t;
  int v = (i < N) ? deg[i] : 0;
  sm[t] = v; __syncthreads();
  #pragma unroll
  for (int off = 1; off < 256; off <<= 1){
    int u = (t >= off) ? sm[t-off] : 0;
    __syncthreads();
    sm[t] += u;
    __syncthreads();
  }
  if (i < N) offs[i] = sm[t] - v;
  if (t == 255) bsum[blockIdx.x] = sm[255];
}

__global__ __launch_bounds__(1024) void scan2_kernel(const int* __restrict__ bsum,
    int* __restrict__ bpre, int NB){
  __shared__ int sm[1024];
  int t = threadIdx.x;
  int v = (t < NB) ? bsum[t] : 0;
  sm[t] = v; __syncthreads();
  #pragma unroll
  for (int off = 1; off < 1024; off <<= 1){
    int u = (t >= off) ? sm[t-off] : 0;
    __syncthreads();
    sm[t] += u;
    __syncthreads();
  }
  if (t < NB) bpre[t] = sm[t] - v;
  if (t == 1023) bpre[NB] = sm[1023];
}

__global__ __launch_bounds__(256) void scan3_kernel(int* __restrict__ offs,
    int* __restrict__ cursor, const int* __restrict__ bpre, int N, int NB){
  int i = blockIdx.x*256 + threadIdx.x;
  if (i < N){
    int v = offs[i] + bpre[blockIdx.x];
    offs[i] = v; cursor[i] = v;
  }
  if (i == 0) offs[N] = bpre[NB];
}

// ---------------- scatter (bid < SB) + prep: btrans/qpart (bid >= SB) ----------------
__global__ __launch_bounds__(256) void scatter_prep_kernel(const int* __restrict__ ei,
    int E, int N, int SB, int* __restrict__ cursor, int* __restrict__ csr_src,
    const void* __restrict__ B1, const void* __restrict__ B2,
    u16* __restrict__ BT1, u16* __restrict__ BT2,
    const void* __restrict__ query, const void* __restrict__ Wc, const void* __restrict__ bc,
    float* __restrict__ qp, int Q, const int* __restrict__ flags){
  int f32 = flags[0];
  int i64 = flags[1];
  int bid = blockIdx.x;
  if (bid < SB){
    int i = bid*256 + threadIdx.x;
    int Et = E + N;
    if (i < Et){
      int s, d;
      if (i < E){
        s = clampi(lde(ei, i, i64), 0, N-1);
        d = clampi(lde(ei, (size_t)E + i, i64), 0, N-1);
      } else { s = i - E; d = s; }
      int p = atomicAdd(&cursor[d], 1);
      csr_src[p] = s;
    }
    return;
  }
  int pb = bid - SB;
  if (pb < 32){
    const void* B = (pb >= 16) ? B2 : B1;
    u16* BT = (pb >= 16) ? BT2 : BT1;
    int rem = pb & 15;
    int k0 = (rem >> 2)*64, c0 = (rem & 3)*64;
    __shared__ u16 tile[64][65];
    int r0 = threadIdx.x >> 6, c = threadIdx.x & 63;
    for (int r = r0; r < 64; r += 4)
      tile[r][c] = f32 ? f2bf(((const float*)B)[(size_t)(k0+r)*256 + c0 + c])
                       : ((const u16*)B)[(size_t)(k0+r)*256 + c0 + c];
    __syncthreads();
    for (int j = r0; j < 64; j += 4)
      BT[(size_t)(c0+j)*256 + k0 + c] = tile[c][j];
  } else {
    int q = threadIdx.x >> 5, ln = threadIdx.x & 31;
    if (q >= Q) return;
    float s = 0.f;
    for (int j = ln; j < 256; j += 32) s += ld1(query, q*256 + j, f32) * ld1(Wc, j, f32);
    #pragma unroll
    for (int off = 16; off; off >>= 1) s += __shfl_down(s, off, 32);
    if (ln == 0) qp[q] = s + ld1(bc, 0, f32);
  }
}

// ---------------- MFMA GEMM: 512 thr, tile 128 rows x 256 cols (round-11 proven) ----------------
// 8 waves (2 row x 4 col); wave wn covers head wn -> fused es/ed is in-wave only.
__global__ __launch_bounds__(512, 4) void gemm_mfma(const void* __restrict__ A,
    const u16* __restrict__ BT, u16* __restrict__ C, int M, int aIsInput,
    const int* __restrict__ flags, float* __restrict__ es, float* __restrict__ ed,
    const void* __restrict__ a_src, const void* __restrict__ a_dst){
  int af32 = aIsInput ? flags[0] : 0;
  int f32 = flags[0];
  __shared__ __align__(16) u16 As[128][40];   // stride-40 pad: 2-way banks (free)
  __shared__ __align__(16) u16 Bs[256][40];
  int tid = threadIdx.x;
  int wave = tid >> 6, lane = tid & 63;
  int wm = wave >> 2, wn = wave & 3;          // 2 row-waves x 4 col-waves
  int l15 = lane & 15, l4 = lane >> 4;
  int row0 = blockIdx.x * 128;
  const u16*  A16 = (const u16*)A;
  const float* A32 = (const float*)A;
  int srow = tid >> 2, sks = (tid & 3) * 8;   // A: 128 rows x 32k, 8 elems/thread
  int scol = tid >> 1, skh = (tid & 1) * 16;  // B: 256 cols x 32k, 16 elems/thread
  int sgr = min(row0 + srow, M-1);
  f32x4 acc[4][4] = {};
  for (int k0 = 0; k0 < 256; k0 += 32){
    __syncthreads();
    { // stage A
      us8 av;
      if (af32){
        const float* ap = A32 + (size_t)sgr*256 + k0 + sks;
        float4 v0 = *(const float4*)ap, v1 = *(const float4*)(ap+4);
        av = (us8){f2bf(v0.x),f2bf(v0.y),f2bf(v0.z),f2bf(v0.w),
                   f2bf(v1.x),f2bf(v1.y),f2bf(v1.z),f2bf(v1.w)};
      } else {
        av = *(const us8*)(A16 + (size_t)sgr*256 + k0 + sks);
      }
      *(us8*)&As[srow][sks] = av;
      // stage B (BT is [col][k] bf16)
      const u16* bp = BT + (size_t)scol*256 + k0 + skh;
      *(us8*)&Bs[scol][skh]   = *(const us8*)bp;
      *(us8*)&Bs[scol][skh+8] = *(const us8*)(bp + 8);
    }
    __syncthreads();
    short8v a[4], b[4];
    #pragma unroll
    for (int mi = 0; mi < 4; mi++)
      a[mi] = *(const short8v*)&As[wm*64 + mi*16 + l15][8*l4];
    #pragma unroll
    for (int ni = 0; ni < 4; ni++)
      b[ni] = *(const short8v*)&Bs[wn*64 + ni*16 + l15][8*l4];
    #pragma unroll
    for (int mi = 0; mi < 4; mi++)
      #pragma unroll
      for (int ni = 0; ni < 4; ni++)
        acc[mi][ni] = __builtin_amdgcn_mfma_f32_16x16x32_bf16(a[mi], b[ni], acc[mi][ni], 0, 0, 0);
  }
  // C store (verified mapping: col=l15, row=l4*4+r within 16x16)
  #pragma unroll
  for (int mi = 0; mi < 4; mi++){
    #pragma unroll
    for (int ni = 0; ni < 4; ni++){
      #pragma unroll
      for (int r = 0; r < 4; r++){
        int row = row0 + wm*64 + mi*16 + l4*4 + r;
        int col = wn*64 + ni*16 + l15;
        if (row < M) C[(size_t)row*256 + col] = f2bf(acc[mi][ni][r]);
      }
    }
  }
  // fused es/ed: wave wn == head wn; reduce over this wave's 64 cols
  float as_[4], ad_[4];
  #pragma unroll
  for (int ni = 0; ni < 4; ni++){
    as_[ni] = ld1(a_src, wn*64 + ni*16 + l15, f32);
    ad_[ni] = ld1(a_dst, wn*64 + ni*16 + l15, f32);
  }
  #pragma unroll
  for (int mi = 0; mi < 4; mi++){
    #pragma unroll
    for (int r = 0; r < 4; r++){
      float pe = acc[mi][0][r]*as_[0] + acc[mi][1][r]*as_[1]
               + acc[mi][2][r]*as_[2] + acc[mi][3][r]*as_[3];
      float pd = acc[mi][0][r]*ad_[0] + acc[mi][1][r]*ad_[1]
               + acc[mi][2][r]*ad_[2] + acc[mi][3][r]*ad_[3];
      #pragma unroll
      for (int off = 1; off < 16; off <<= 1){
        pe += __shfl_xor(pe, off, 64);
        pd += __shfl_xor(pd, off, 64);
      }
      if (l15 == 0){
        int row = row0 + wm*64 + mi*16 + l4*4 + r;
        if (row < M){
          es[(size_t)row*4 + wn] = pe;
          ed[(size_t)row*4 + wn] = pd;
        }
      }
    }
  }
}

// ---------------- fused aggregation (exact round-4 body) + nscore epilogue ----------------
__global__ __launch_bounds__(256) void agg_kernel(const u16* __restrict__ h,
    const int* __restrict__ csr_src, const int* __restrict__ offs,
    const float* __restrict__ es, const float* __restrict__ ed, int N,
    const void* __restrict__ bias, void* __restrict__ out, int do_relu, int outIsOutput,
    const int* __restrict__ flags, const void* __restrict__ Wc,
    const float* __restrict__ qp, int Q){
  int f32in = flags[0];
  int of32  = outIsOutput ? flags[0] : 0;
  int ln = threadIdx.x & 63;
  int n = blockIdx.x*4 + (threadIdx.x >> 6);
  if (n >= N) return;
  int beg = offs[n], end = offs[n+1];
  int hd = ln >> 4, c0 = ln*4;
  float edn = ed[(size_t)n*4 + hd];
  float a0=0.f, a1=0.f, a2=0.f, a3=0.f, ws=0.f;
  int i = beg;
  for (; i + 8 <= end; i += 8){
    int s[8]; float x[8]; ushort4 hv[8];
    #pragma unroll
    for (int j = 0; j < 8; j++) s[j] = csr_src[i+j];
    #pragma unroll
    for (int j = 0; j < 8; j++) x[j] = es[(size_t)s[j]*4 + hd];
    #pragma unroll
    for (int j = 0; j < 8; j++) hv[j] = *(const ushort4*)&h[(size_t)s[j]*256 + c0];
    #pragma unroll
    for (int j = 0; j < 8; j++){
      float t = x[j] + edn; t = (t > 0.f) ? t : 0.2f*t; t = fminf(t, 60.f);
      float w = __expf(t);
      a0 += w*bf2f(hv[j].x); a1 += w*bf2f(hv[j].y);
      a2 += w*bf2f(hv[j].z); a3 += w*bf2f(hv[j].w);
      ws += w;
    }
  }
  for (; i + 4 <= end; i += 4){
    int s[4]; float x[4]; ushort4 hv[4];
    #pragma unroll
    for (int j = 0; j < 4; j++) s[j] = csr_src[i+j];
    #pragma unroll
    for (int j = 0; j < 4; j++) x[j] = es[(size_t)s[j]*4 + hd];
    #pragma unroll
    for (int j = 0; j < 4; j++) hv[j] = *(const ushort4*)&h[(size_t)s[j]*256 + c0];
    #pragma unroll
    for (int j = 0; j < 4; j++){
      float t = x[j] + edn; t = (t > 0.f) ? t : 0.2f*t; t = fminf(t, 60.f);
      float w = __expf(t);
      a0 += w*bf2f(hv[j].x); a1 += w*bf2f(hv[j].y);
      a2 += w*bf2f(hv[j].z); a3 += w*bf2f(hv[j].w);
      ws += w;
    }
  }
  for (; i < end; i++){
    int s = csr_src[i];
    float t = es[(size_t)s*4 + hd] + edn; t = (t > 0.f) ? t : 0.2f*t; t = fminf(t, 60.f);
    float w = __expf(t);
    ushort4 hv = *(const ushort4*)&h[(size_t)s*256 + c0];
    a0 += w*bf2f(hv.x); a1 += w*bf2f(hv.y);
    a2 += w*bf2f(hv.z); a3 += w*bf2f(hv.w);
    ws += w;
  }
  float inv = 1.f / (ws + 1e-16f);
  float4 bv = ld4(bias, c0, f32in);
  float4 ov = make_float4(a0*inv + bv.x, a1*inv + bv.y, a2*inv + bv.z, a3*inv + bv.w);
  if (do_relu){
    ov.x = fmaxf(ov.x, 0.f); ov.y = fmaxf(ov.y, 0.f);
    ov.z = fmaxf(ov.z, 0.f); ov.w = fmaxf(ov.w, 0.f);
  }
  st4(out, (size_t)n*256 + c0, ov, of32);
  if (outIsOutput){
    float4 wc4 = ld4(Wc, 256 + c0, f32in);
    float v = ov.x*wc4.x + ov.y*wc4.y + ov.z*wc4.z + ov.w*wc4.w;
    #pragma unroll
    for (int off = 1; off < 64; off <<= 1) v += __shfl_xor(v, off, 64);
    if (ln < Q) st1(out, (size_t)N*256 + (size_t)ln*N + n, qp[ln] + v, of32);
  }
}

extern "C" void kernel_launch(void* const* d_in, const int* in_sizes, int n_in,
                              void* d_out, int out_size, void* d_ws, size_t ws_size,
                              hipStream_t stream){
  const void* x     = d_in[0];
  const int*  ei    = (const int*)d_in[1];
  const void* query = d_in[2];
  const void* W1    = d_in[3];
  const void* as1   = d_in[4];
  const void* ad1   = d_in[5];
  const void* b1    = d_in[6];
  const void* W2    = d_in[7];
  const void* as2   = d_in[8];
  const void* ad2   = d_in[9];
  const void* b2    = d_in[10];
  const void* Wc    = d_in[11];
  const void* bc    = d_in[12];

  int N = in_sizes[0] / 256;
  int E = in_sizes[1] / 2;
  int Q = in_sizes[2] / 256;
  int Et = E + N;
  int NB = (N + 255) / 256;
  int SB = (Et + 255) / 256;

  char* p = (char*)d_ws;
  auto alloc = [&](size_t bytes)->char*{
    char* r = p; p += (bytes + 255) & ~(size_t)255; return r;
  };
  int*  flags    = (int*) alloc(256);
  u16*  bufA     = (u16*) alloc((size_t)N*256*2);
  u16*  bufB     = (u16*) alloc((size_t)N*256*2);
  float* es      = (float*)alloc((size_t)N*4*4);
  float* ed      = (float*)alloc((size_t)N*4*4);
  int*  deg      = (int*)  alloc((size_t)N*4);
  int*  offs     = (int*)  alloc((size_t)(N+1)*4);
  int*  cursor   = (int*)  alloc((size_t)N*4);
  int*  csr_src  = (int*)  alloc((size_t)Et*4);
  int*  bsum     = (int*)  alloc((size_t)(NB+1)*4);
  int*  bpre     = (int*)  alloc((size_t)(NB+1)*4);
  u16*  BT1      = (u16*)  alloc(256*256*2);
  u16*  BT2      = (u16*)  alloc(256*256*2);
  float* qp      = (float*)alloc(64*4);

  const int thr = 256;
  detect_zero_kernel<<<NB + 1, 256, 0, stream>>>((const u32*)x, ei, flags, deg, N);
  count_kernel <<<(Et + thr-1)/thr, thr, 0, stream>>>(ei, E, N, deg, flags);
  scan1_kernel <<<NB, 256, 0, stream>>>(deg, offs, bsum, N);
  scan2_kernel <<<1, 1024, 0, stream>>>(bsum, bpre, NB);
  scan3_kernel <<<NB, 256, 0, stream>>>(offs, cursor, bpre, N, NB);
  scatter_prep_kernel<<<SB + 33, 256, 0, stream>>>(ei, E, N, SB, cursor, csr_src,
                                                   W1, W2, BT1, BT2, query, Wc, bc,
                                                   qp, Q, flags);

  int gblocks = (N + 127)/128;
  dim3 ngrid((N + 3)/4);

  // ---- layer 1 ----
  gemm_mfma <<<gblocks, 512, 0, stream>>>(x, BT1, bufA, N, 1, flags, es, ed, as1, ad1);
  agg_kernel<<<ngrid, 256, 0, stream>>>(bufA, csr_src, offs, es, ed, N, b1, bufB, 1, 0,
                                        flags, Wc, qp, Q);
  // ---- layer 2 ----
  gemm_mfma <<<gblocks, 512, 0, stream>>>(bufB, BT2, bufA, N, 0, flags, es, ed, as2, ad2);
  agg_kernel<<<ngrid, 256, 0, stream>>>(bufA, csr_src, offs, es, ed, N, b2, d_out, 0, 1,
                                        flags, Wc, qp, Q);
}

// Round 17
// 297.070 us; speedup vs baseline: 1.1838x; 1.0123x over previous
//
#include <hip/hip_runtime.h>

typedef unsigned short u16;
typedef unsigned int   u32;
typedef __attribute__((ext_vector_type(8))) short short8v;
typedef __attribute__((ext_vector_type(8))) unsigned short us8;
typedef __attribute__((ext_vector_type(4))) float f32x4;

static __device__ __forceinline__ float bf2f(u16 u){ union{u32 i; float f;} v; v.i=(u32)u<<16; return v.f; }
static __device__ __forceinline__ u16 f2bf(float f){ union{float f; u32 i;} u; u.f=f; u32 r=u.i+0x7FFFu+((u.i>>16)&1u); return (u16)(r>>16); }

static __device__ __forceinline__ float ld1(const void* p, size_t i, int f32){
  return f32 ? ((const float*)p)[i] : bf2f(((const u16*)p)[i]);
}
static __device__ __forceinline__ float4 ld4(const void* p, size_t i, int f32){
  if (f32) return *((const float4*)((const float*)p + i));
  ushort4 v = *((const ushort4*)((const u16*)p + i));
  return make_float4(bf2f(v.x), bf2f(v.y), bf2f(v.z), bf2f(v.w));
}
static __device__ __forceinline__ void st4(void* p, size_t i, float4 v, int f32){
  if (f32) *((float4*)((float*)p + i)) = v;
  else { ushort4 o; o.x=f2bf(v.x); o.y=f2bf(v.y); o.z=f2bf(v.z); o.w=f2bf(v.w); *((ushort4*)((u16*)p + i)) = o; }
}
static __device__ __forceinline__ void st1(void* p, size_t i, float v, int f32){
  if (f32) ((float*)p)[i] = v; else ((u16*)p)[i] = f2bf(v);
}
static __device__ __forceinline__ int lde(const int* ei, size_t i, int i64){
  return i64 ? ei[2*i] : ei[i];
}
static __device__ __forceinline__ int clampi(int v, int lo, int hi){ return v<lo?lo:(v>hi?hi:v); }

// ---------------- detect dtypes (block 0) + zero deg (blocks 1..) ----------------
__global__ void detect_zero_kernel(const u32* __restrict__ x, const int* __restrict__ ei,
                                   int* __restrict__ flags, int* __restrict__ deg, int N){
  if (blockIdx.x != 0){
    int i = (blockIdx.x - 1)*256 + threadIdx.x;
    if (i < N) deg[i] = 0;
    return;
  }
  __shared__ int cnt[2];
  int t = threadIdx.x;
  if (t < 2) cnt[t] = 0;
  __syncthreads();
  int good = 0;
  for (int i = t; i < 4096; i += 256){
    u32 e = (x[i] >> 7) & 0xFFu;
    if (e >= 90u && e <= 150u) good++;
  }
  atomicAdd(&cnt[0], good);
  int nzodd = 0;
  for (int i = t; i < 2048; i += 256){
    if (ei[2*i+1] != 0) nzodd++;
  }
  atomicAdd(&cnt[1], nzodd);
  __syncthreads();
  if (t == 0){
    flags[0] = (cnt[0] < 2867) ? 1 : 0;
    flags[1] = (cnt[1] == 0) ? 1 : 0;
  }
}

// ---------------- CSR build ----------------
__global__ void count_kernel(const int* __restrict__ ei, int E, int N,
                             int* __restrict__ deg, const int* __restrict__ flags){
  int i64 = flags[1];
  int i = blockIdx.x*blockDim.x + threadIdx.x;
  int Et = E + N;
  if (i < Et){
    int d = (i < E) ? clampi(lde(ei, (size_t)E + i, i64), 0, N-1) : (i - E);
    atomicAdd(&deg[d], 1);
  }
}

__global__ __launch_bounds__(256) void scan1_kernel(const int* __restrict__ deg,
    int* __restrict__ offs, int* __restrict__ bsum, int N){
  __shared__ int sm[256];
  int t = threadIdx.x;
  int i = blockIdx.x*256 + t;
  int v = (i < N) ? deg[i] : 0;
  sm[t] = v; __syncthreads();
  #pragma unroll
  for (int off = 1; off < 256; off <<= 1){
    int u = (t >= off) ? sm[t-off] : 0;
    __syncthreads();
    sm[t] += u;
    __syncthreads();
  }
  if (i < N) offs[i] = sm[t] - v;
  if (t == 255) bsum[blockIdx.x] = sm[255];
}

__global__ __launch_bounds__(1024) void scan2_kernel(const int* __restrict__ bsum,
    int* __restrict__ bpre, int NB){
  __shared__ int sm[1024];
  int t = threadIdx.x;
  int v = (t < NB) ? bsum[t] : 0;
  sm[t] = v; __syncthreads();
  #pragma unroll
  for (int off = 1; off < 1024; off <<= 1){
    int u = (t >= off) ? sm[t-off] : 0;
    __syncthreads();
    sm[t] += u;
    __syncthreads();
  }
  if (t < NB) bpre[t] = sm[t] - v;
  if (t == 1023) bpre[NB] = sm[1023];
}

__global__ __launch_bounds__(256) void scan3_kernel(int* __restrict__ offs,
    int* __restrict__ cursor, const int* __restrict__ bpre, int N, int NB){
  int i = blockIdx.x*256 + threadIdx.x;
  if (i < N){
    int v = offs[i] + bpre[blockIdx.x];
    offs[i] = v; cursor[i] = v;
  }
  if (i == 0) offs[N] = bpre[NB];
}

// ---------------- scatter (bid < SB) + prep: btrans/qpart (bid >= SB) ----------------
__global__ __launch_bounds__(256) void scatter_prep_kernel(const int* __restrict__ ei,
    int E, int N, int SB, int* __restrict__ cursor, int* __restrict__ csr_src,
    const void* __restrict__ B1, const void* __restrict__ B2,
    u16* __restrict__ BT1, u16* __restrict__ BT2,
    const void* __restrict__ query, const void* __restrict__ Wc, const void* __restrict__ bc,
    float* __restrict__ qp, int Q, const int* __restrict__ flags){
  int f32 = flags[0];
  int i64 = flags[1];
  int bid = blockIdx.x;
  if (bid < SB){
    int i = bid*256 + threadIdx.x;
    int Et = E + N;
    if (i < Et){
      int s, d;
      if (i < E){
        s = clampi(lde(ei, i, i64), 0, N-1);
        d = clampi(lde(ei, (size_t)E + i, i64), 0, N-1);
      } else { s = i - E; d = s; }
      int p = atomicAdd(&cursor[d], 1);
      csr_src[p] = s;
    }
    return;
  }
  int pb = bid - SB;
  if (pb < 32){
    const void* B = (pb >= 16) ? B2 : B1;
    u16* BT = (pb >= 16) ? BT2 : BT1;
    int rem = pb & 15;
    int k0 = (rem >> 2)*64, c0 = (rem & 3)*64;
    __shared__ u16 tile[64][65];
    int r0 = threadIdx.x >> 6, c = threadIdx.x & 63;
    for (int r = r0; r < 64; r += 4)
      tile[r][c] = f32 ? f2bf(((const float*)B)[(size_t)(k0+r)*256 + c0 + c])
                       : ((const u16*)B)[(size_t)(k0+r)*256 + c0 + c];
    __syncthreads();
    for (int j = r0; j < 64; j += 4)
      BT[(size_t)(c0+j)*256 + k0 + c] = tile[c][j];
  } else {
    int q = threadIdx.x >> 5, ln = threadIdx.x & 31;
    if (q >= Q) return;
    float s = 0.f;
    for (int j = ln; j < 256; j += 32) s += ld1(query, q*256 + j, f32) * ld1(Wc, j, f32);
    #pragma unroll
    for (int off = 16; off; off >>= 1) s += __shfl_down(s, off, 32);
    if (ln == 0) qp[q] = s + ld1(bc, 0, f32);
  }
}

// ---------------- MFMA GEMM: 512 thr, tile 128x256, LDS-repacked coalesced C store ----------------
__global__ __launch_bounds__(512, 4) void gemm_mfma(const void* __restrict__ A,
    const u16* __restrict__ BT, u16* __restrict__ C, int M, int aIsInput,
    const int* __restrict__ flags, float* __restrict__ es, float* __restrict__ ed,
    const void* __restrict__ a_src, const void* __restrict__ a_dst){
  int af32 = aIsInput ? flags[0] : 0;
  int f32 = flags[0];
  __shared__ __align__(16) u16 smem[128*40 + 256*40];   // As | Bs; reused for C repack
  u16* AsB = smem;                 // As[row][k] stride 40
  u16* BsB = smem + 128*40;        // Bs[col][k] stride 40
  int tid = threadIdx.x;
  int wave = tid >> 6, lane = tid & 63;
  int wm = wave >> 2, wn = wave & 3;
  int l15 = lane & 15, l4 = lane >> 4;
  int row0 = blockIdx.x * 128;
  const u16*  A16 = (const u16*)A;
  const float* A32 = (const float*)A;
  int srow = tid >> 2, sks = (tid & 3) * 8;
  int scol = tid >> 1, skh = (tid & 1) * 16;
  int sgr = min(row0 + srow, M-1);
  f32x4 acc[4][4] = {};
  for (int k0 = 0; k0 < 256; k0 += 32){
    __syncthreads();
    {
      us8 av;
      if (af32){
        const float* ap = A32 + (size_t)sgr*256 + k0 + sks;
        float4 v0 = *(const float4*)ap, v1 = *(const float4*)(ap+4);
        av = (us8){f2bf(v0.x),f2bf(v0.y),f2bf(v0.z),f2bf(v0.w),
                   f2bf(v1.x),f2bf(v1.y),f2bf(v1.z),f2bf(v1.w)};
      } else {
        av = *(const us8*)(A16 + (size_t)sgr*256 + k0 + sks);
      }
      *(us8*)&AsB[srow*40 + sks] = av;
      const u16* bp = BT + (size_t)scol*256 + k0 + skh;
      *(us8*)&BsB[scol*40 + skh]     = *(const us8*)bp;
      *(us8*)&BsB[scol*40 + skh + 8] = *(const us8*)(bp + 8);
    }
    __syncthreads();
    short8v a[4], b[4];
    #pragma unroll
    for (int mi = 0; mi < 4; mi++)
      a[mi] = *(const short8v*)&AsB[(wm*64 + mi*16 + l15)*40 + 8*l4];
    #pragma unroll
    for (int ni = 0; ni < 4; ni++)
      b[ni] = *(const short8v*)&BsB[(wn*64 + ni*16 + l15)*40 + 8*l4];
    #pragma unroll
    for (int mi = 0; mi < 4; mi++)
      #pragma unroll
      for (int ni = 0; ni < 4; ni++)
        acc[mi][ni] = __builtin_amdgcn_mfma_f32_16x16x32_bf16(a[mi], b[ni], acc[mi][ni], 0, 0, 0);
  }
  // fused es/ed first (register-only): wave wn == head wn
  float as_[4], ad_[4];
  #pragma unroll
  for (int ni = 0; ni < 4; ni++){
    as_[ni] = ld1(a_src, wn*64 + ni*16 + l15, f32);
    ad_[ni] = ld1(a_dst, wn*64 + ni*16 + l15, f32);
  }
  #pragma unroll
  for (int mi = 0; mi < 4; mi++){
    #pragma unroll
    for (int r = 0; r < 4; r++){
      float pe = acc[mi][0][r]*as_[0] + acc[mi][1][r]*as_[1]
               + acc[mi][2][r]*as_[2] + acc[mi][3][r]*as_[3];
      float pd = acc[mi][0][r]*ad_[0] + acc[mi][1][r]*ad_[1]
               + acc[mi][2][r]*ad_[2] + acc[mi][3][r]*ad_[3];
      #pragma unroll
      for (int off = 1; off < 16; off <<= 1){
        pe += __shfl_xor(pe, off, 64);
        pd += __shfl_xor(pd, off, 64);
      }
      if (l15 == 0){
        int row = row0 + wm*64 + mi*16 + l4*4 + r;
        if (row < M){
          es[(size_t)row*4 + wn] = pe;
          ed[(size_t)row*4 + wn] = pd;
        }
      }
    }
  }
  // C store via LDS repack: per mi, tile [32 rows][264 stride], then coalesced us8 stores
  u16* tile = smem;     // 32*264*2 = 16.9KB <= 30KB staging (staging reads all done)
  __syncthreads();
  #pragma unroll
  for (int mi = 0; mi < 4; mi++){
    #pragma unroll
    for (int ni = 0; ni < 4; ni++)
      #pragma unroll
      for (int r = 0; r < 4; r++)
        tile[(wm*16 + l4*4 + r)*264 + wn*64 + ni*16 + l15] = f2bf(acc[mi][ni][r]);
    __syncthreads();
    #pragma unroll
    for (int c = tid; c < 1024; c += 512){
      int lr = c >> 5, col = (c & 31) * 8;
      int grow = row0 + (lr >> 4)*64 + mi*16 + (lr & 15);
      if (grow < M)
        *(us8*)&C[(size_t)grow*256 + col] = *(const us8*)&tile[lr*264 + col];
    }
    __syncthreads();
  }
}

// ---------------- fused aggregation (round-4 body) + nscore epilogue ----------------
__global__ __launch_bounds__(256) void agg_kernel(const u16* __restrict__ h,
    const int* __restrict__ csr_src, const int* __restrict__ offs,
    const float* __restrict__ es, const float* __restrict__ ed, int N,
    const void* __restrict__ bias, void* __restrict__ out, int do_relu, int outIsOutput,
    const int* __restrict__ flags, const void* __restrict__ Wc,
    const float* __restrict__ qp, int Q){
  int f32in = flags[0];
  int of32  = outIsOutput ? flags[0] : 0;
  int ln = threadIdx.x & 63;
  int n = blockIdx.x*4 + (threadIdx.x >> 6);
  if (n >= N) return;
  int beg = offs[n], end = offs[n+1];
  int hd = ln >> 4, c0 = ln*4;
  float edn = ed[(size_t)n*4 + hd];
  float a0=0.f, a1=0.f, a2=0.f, a3=0.f, ws=0.f;
  int i = beg;
  for (; i + 8 <= end; i += 8){
    int s[8]; float x[8]; ushort4 hv[8];
    #pragma unroll
    for (int j = 0; j < 8; j++) s[j] = csr_src[i+j];
    #pragma unroll
    for (int j = 0; j < 8; j++) x[j] = es[(size_t)s[j]*4 + hd];
    #pragma unroll
    for (int j = 0; j < 8; j++) hv[j] = *(const ushort4*)&h[(size_t)s[j]*256 + c0];
    #pragma unroll
    for (int j = 0; j < 8; j++){
      float t = x[j] + edn; t = (t > 0.f) ? t : 0.2f*t; t = fminf(t, 60.f);
      float w = __expf(t);
      a0 += w*bf2f(hv[j].x); a1 += w*bf2f(hv[j].y);
      a2 += w*bf2f(hv[j].z); a3 += w*bf2f(hv[j].w);
      ws += w;
    }
  }
  for (; i + 4 <= end; i += 4){
    int s[4]; float x[4]; ushort4 hv[4];
    #pragma unroll
    for (int j = 0; j < 4; j++) s[j] = csr_src[i+j];
    #pragma unroll
    for (int j = 0; j < 4; j++) x[j] = es[(size_t)s[j]*4 + hd];
    #pragma unroll
    for (int j = 0; j < 4; j++) hv[j] = *(const ushort4*)&h[(size_t)s[j]*256 + c0];
    #pragma unroll
    for (int j = 0; j < 4; j++){
      float t = x[j] + edn; t = (t > 0.f) ? t : 0.2f*t; t = fminf(t, 60.f);
      float w = __expf(t);
      a0 += w*bf2f(hv[j].x); a1 += w*bf2f(hv[j].y);
      a2 += w*bf2f(hv[j].z); a3 += w*bf2f(hv[j].w);
      ws += w;
    }
  }
  for (; i < end; i++){
    int s = csr_src[i];
    float t = es[(size_t)s*4 + hd] + edn; t = (t > 0.f) ? t : 0.2f*t; t = fminf(t, 60.f);
    float w = __expf(t);
    ushort4 hv = *(const ushort4*)&h[(size_t)s*256 + c0];
    a0 += w*bf2f(hv.x); a1 += w*bf2f(hv.y);
    a2 += w*bf2f(hv.z); a3 += w*bf2f(hv.w);
    ws += w;
  }
  float inv = 1.f / (ws + 1e-16f);
  float4 bv = ld4(bias, c0, f32in);
  float4 ov = make_float4(a0*inv + bv.x, a1*inv + bv.y, a2*inv + bv.z, a3*inv + bv.w);
  if (do_relu){
    ov.x = fmaxf(ov.x, 0.f); ov.y = fmaxf(ov.y, 0.f);
    ov.z = fmaxf(ov.z, 0.f); ov.w = fmaxf(ov.w, 0.f);
  }
  st4(out, (size_t)n*256 + c0, ov, of32);
  if (outIsOutput){
    float4 wc4 = ld4(Wc, 256 + c0, f32in);
    float v = ov.x*wc4.x + ov.y*wc4.y + ov.z*wc4.z + ov.w*wc4.w;
    #pragma unroll
    for (int off = 1; off < 64; off <<= 1) v += __shfl_xor(v, off, 64);
    if (ln < Q) st1(out, (size_t)N*256 + (size_t)ln*N + n, qp[ln] + v, of32);
  }
}

extern "C" void kernel_launch(void* const* d_in, const int* in_sizes, int n_in,
                              void* d_out, int out_size, void* d_ws, size_t ws_size,
                              hipStream_t stream){
  const void* x     = d_in[0];
  const int*  ei    = (const int*)d_in[1];
  const void* query = d_in[2];
  const void* W1    = d_in[3];
  const void* as1   = d_in[4];
  const void* ad1   = d_in[5];
  const void* b1    = d_in[6];
  const void* W2    = d_in[7];
  const void* as2   = d_in[8];
  const void* ad2   = d_in[9];
  const void* b2    = d_in[10];
  const void* Wc    = d_in[11];
  const void* bc    = d_in[12];

  int N = in_sizes[0] / 256;
  int E = in_sizes[1] / 2;
  int Q = in_sizes[2] / 256;
  int Et = E + N;
  int NB = (N + 255) / 256;
  int SB = (Et + 255) / 256;

  char* p = (char*)d_ws;
  auto alloc = [&](size_t bytes)->char*{
    char* r = p; p += (bytes + 255) & ~(size_t)255; return r;
  };
  int*  flags    = (int*) alloc(256);
  u16*  bufA     = (u16*) alloc((size_t)N*256*2);
  u16*  bufB     = (u16*) alloc((size_t)N*256*2);
  float* es      = (float*)alloc((size_t)N*4*4);
  float* ed      = (float*)alloc((size_t)N*4*4);
  int*  deg      = (int*)  alloc((size_t)N*4);
  int*  offs     = (int*)  alloc((size_t)(N+1)*4);
  int*  cursor   = (int*)  alloc((size_t)N*4);
  int*  csr_src  = (int*)  alloc((size_t)Et*4);
  int*  bsum     = (int*)  alloc((size_t)(NB+1)*4);
  int*  bpre     = (int*)  alloc((size_t)(NB+1)*4);
  u16*  BT1      = (u16*)  alloc(256*256*2);
  u16*  BT2      = (u16*)  alloc(256*256*2);
  float* qp      = (float*)alloc(64*4);

  const int thr = 256;
  detect_zero_kernel<<<NB + 1, 256, 0, stream>>>((const u32*)x, ei, flags, deg, N);
  count_kernel <<<(Et + thr-1)/thr, thr, 0, stream>>>(ei, E, N, deg, flags);
  scan1_kernel <<<NB, 256, 0, stream>>>(deg, offs, bsum, N);
  scan2_kernel <<<1, 1024, 0, stream>>>(bsum, bpre, NB);
  scan3_kernel <<<NB, 256, 0, stream>>>(offs, cursor, bpre, N, NB);
  scatter_prep_kernel<<<SB + 33, 256, 0, stream>>>(ei, E, N, SB, cursor, csr_src,
                                                   W1, W2, BT1, BT2, query, Wc, bc,
                                                   qp, Q, flags);

  int gblocks = (N + 127)/128;
  dim3 ngrid((N + 3)/4);

  // ---- layer 1 ----
  gemm_mfma <<<gblocks, 512, 0, stream>>>(x, BT1, bufA, N, 1, flags, es, ed, as1, ad1);
  agg_kernel<<<ngrid, 256, 0, stream>>>(bufA, csr_src, offs, es, ed, N, b1, bufB, 1, 0,
                                        flags, Wc, qp, Q);
  // ---- layer 2 ----
  gemm_mfma <<<gblocks, 512, 0, stream>>>(bufB, BT2, bufA, N, 0, flags, es, ed, as2, ad2);
  agg_kernel<<<ngrid, 256, 0, stream>>>(bufA, csr_src, offs, es, ed, N, b2, d_out, 0, 1,
                                        flags, Wc, qp, Q);
}